// Round 1
// baseline (778.333 us; speedup 1.0000x reference)
//
#include <hip/hip_runtime.h>
#include <math.h>

#define LN_EPS 1e-5f

// ws layout:
//   Wcat : [1024][192] f32 at offset 0        (gamma-folded ternary weights; cols 0-63=q, 64-127=k, 128-191=v)
//   cvec : [192]       f32 at offset 786432   (beta-folded bias per output col)
//   qkv  : [16384][192] f32 at offset 1048576

// ---------------- quantize weights + fold gamma/beta ----------------
__global__ __launch_bounds__(1024) void quant_k(
    const float* __restrict__ Wq, const float* __restrict__ Wk, const float* __restrict__ Wv,
    const float* __restrict__ gq, const float* __restrict__ bq,
    const float* __restrict__ gk, const float* __restrict__ bk,
    const float* __restrict__ gv, const float* __restrict__ bv,
    float* __restrict__ Wcat, float* __restrict__ cvec)
{
    const int br = blockIdx.x;                 // 0=q, 1=k, 2=v
    const float* W = (br==0) ? Wq : (br==1 ? Wk : Wv);
    const float* g = (br==0) ? gq : (br==1 ? gk : gv);
    const float* bb= (br==0) ? bq : (br==1 ? bk : bv);
    const int t = threadIdx.x;
    __shared__ float red[1024];
    float s = 0.f;
    #pragma unroll 4
    for (int i=0;i<64;i++) s += fabsf(W[t + 1024*i]);
    red[t] = s;
    __syncthreads();
    for (int o=512;o>0;o>>=1){ if (t<o) red[t]+=red[t+o]; __syncthreads(); }
    const float mean = red[0] * (1.0f/65536.0f);   // exact /2^16

    // quantize row e=t, fold gamma
    const float ge = g[t];
    for (int h=0; h<64; h++) {
        float w  = W[t*64+h];
        float wq = fminf(1.f, fmaxf(-1.f, rintf(w/mean)));   // round-half-even like jnp.round
        Wcat[t*192 + br*64 + h] = ge*wq;
    }
    // fold beta: cvec[br*64+h] = sum_e b[e]*wq(e,h)
    const int h = t & 63, chunk = t >> 6;
    float cp = 0.f;
    for (int i=0;i<64;i++){
        int e = chunk*64 + i;
        float w  = W[e*64+h];
        float wq = fminf(1.f, fmaxf(-1.f, rintf(w/mean)));
        cp += bb[e]*wq;
    }
    __shared__ float cred[16][64];
    cred[chunk][h] = cp;
    __syncthreads();
    if (t < 64){
        float c = 0.f;
        #pragma unroll
        for (int i=0;i<16;i++) c += cred[i][t];
        cvec[br*64 + t] = c;
    }
}

// ---------------- fused LayerNorm + ternary QKV GEMM ----------------
// C[16384x192] = LN(x)[16384x1024] @ Wcat[1024x192] + cvec
// BM=64, BK=16, BN=192, 256 threads, reg-prefetch double buffer.
__global__ __launch_bounds__(256) void lngemm_k(
    const float* __restrict__ x, const float* __restrict__ Wcat,
    const float* __restrict__ cvec, float* __restrict__ qkv)
{
    __shared__ float As[16][68];     // [k][m], padded
    __shared__ float Bs[16][192];    // [k][n]
    __shared__ float mu_s[64], rs_s[64];
    const int t  = threadIdx.x;
    const int r0 = blockIdx.x * 64;

    const int arow = t >> 2, apart = t & 3;        // A loads: row, 16B chunk
    const int bkk  = t >> 4, bn   = (t & 15) * 12; // B loads: row kk, 12 cols

    // prefetch tile 0
    float4 aV = *(const float4*)(x + (r0 + arow)*1024 + apart*4);
    const float* wr0 = Wcat + bkk*192 + bn;
    float4 bV0 = *(const float4*)(wr0);
    float4 bV1 = *(const float4*)(wr0+4);
    float4 bV2 = *(const float4*)(wr0+8);

    // LN stats (4 threads per row)
    {
        const float* xr = x + (r0 + arow)*1024 + apart*4;
        float s1=0.f, s2=0.f;
        #pragma unroll 8
        for (int j=0;j<64;j++){
            float4 v = *(const float4*)(xr + j*16);
            s1 += v.x+v.y+v.z+v.w;
            s2 += v.x*v.x+v.y*v.y+v.z*v.z+v.w*v.w;
        }
        s1 += __shfl_xor(s1,1); s1 += __shfl_xor(s1,2);
        s2 += __shfl_xor(s2,1); s2 += __shfl_xor(s2,2);
        if (apart==0){
            float mu  = s1*(1.f/1024.f);
            float var = s2*(1.f/1024.f) - mu*mu;
            mu_s[arow]=mu; rs_s[arow]=rsqrtf(var+LN_EPS);
        }
    }
    __syncthreads();
    const float mu = mu_s[arow], rs = rs_s[arow];

    const int tx = t & 15, ty = t >> 4;   // output tile: rows ty*4+mi, cols tx*4+64c
    float4 c0 = *(const float4*)(cvec + tx*4);
    float4 c1 = *(const float4*)(cvec + tx*4 + 64);
    float4 c2 = *(const float4*)(cvec + tx*4 + 128);
    float4 acc[4][3];
    #pragma unroll
    for (int mi=0;mi<4;mi++){ acc[mi][0]=c0; acc[mi][1]=c1; acc[mi][2]=c2; }

    for (int kt=0; kt<64; kt++){
        As[apart*4+0][arow] = (aV.x-mu)*rs;
        As[apart*4+1][arow] = (aV.y-mu)*rs;
        As[apart*4+2][arow] = (aV.z-mu)*rs;
        As[apart*4+3][arow] = (aV.w-mu)*rs;
        *(float4*)&Bs[bkk][bn+0] = bV0;
        *(float4*)&Bs[bkk][bn+4] = bV1;
        *(float4*)&Bs[bkk][bn+8] = bV2;
        __syncthreads();
        if (kt < 63){
            aV = *(const float4*)(x + (r0 + arow)*1024 + (kt+1)*16 + apart*4);
            const float* wr = Wcat + ((kt+1)*16 + bkk)*192 + bn;
            bV0 = *(const float4*)(wr);
            bV1 = *(const float4*)(wr+4);
            bV2 = *(const float4*)(wr+8);
        }
        #pragma unroll
        for (int kk=0;kk<16;kk++){
            float4 a4  = *(const float4*)&As[kk][ty*4];
            float4 b40 = *(const float4*)&Bs[kk][tx*4];
            float4 b41 = *(const float4*)&Bs[kk][tx*4+64];
            float4 b42 = *(const float4*)&Bs[kk][tx*4+128];
            float am[4] = {a4.x, a4.y, a4.z, a4.w};
            #pragma unroll
            for (int mi=0;mi<4;mi++){
                acc[mi][0].x += am[mi]*b40.x; acc[mi][0].y += am[mi]*b40.y;
                acc[mi][0].z += am[mi]*b40.z; acc[mi][0].w += am[mi]*b40.w;
                acc[mi][1].x += am[mi]*b41.x; acc[mi][1].y += am[mi]*b41.y;
                acc[mi][1].z += am[mi]*b41.z; acc[mi][1].w += am[mi]*b41.w;
                acc[mi][2].x += am[mi]*b42.x; acc[mi][2].y += am[mi]*b42.y;
                acc[mi][2].z += am[mi]*b42.z; acc[mi][2].w += am[mi]*b42.w;
            }
        }
        __syncthreads();
    }
    #pragma unroll
    for (int mi=0;mi<4;mi++){
        float* outr = qkv + (r0 + ty*4 + mi)*192;
        *(float4*)(outr + tx*4)       = acc[mi][0];
        *(float4*)(outr + tx*4 + 64)  = acc[mi][1];
        *(float4*)(outr + tx*4 + 128) = acc[mi][2];
    }
}

// ---------------- flash attention (fp32, non-causal) ----------------
// grid 256 = 4 batches x 64 q-tiles of 64 rows; 256 threads; 4x4 reg tiles.
__global__ __launch_bounds__(256) void attn_k(
    const float* __restrict__ qkv, float* __restrict__ out)
{
    __shared__ float Qs[64][64];     // [d][q], Q pre-scaled by 1/8
    __shared__ float KsPs[64][68];   // [k][d] during S; reused as P[q][k] for PV
    __shared__ float Vs[64][64];     // [k][h]
    const int t  = threadIdx.x;
    const int tx = t & 15, ty = t >> 4;
    const int b  = blockIdx.x >> 6;
    const int qt = blockIdx.x & 63;
    const int rb = b * 4096;
    const int q0 = rb + qt * 64;

    int rowi[4], coli[4];
    #pragma unroll
    for (int i=0;i<4;i++){
        int f4 = t + 256*i;
        rowi[i] = f4 >> 4;
        coli[i] = (f4 & 15) * 4;
    }
    // load Q transposed + pre-scale
    #pragma unroll
    for (int i=0;i<4;i++){
        float4 v = *(const float4*)(qkv + (q0 + rowi[i])*192 + coli[i]);
        Qs[coli[i]+0][rowi[i]] = v.x * 0.125f;
        Qs[coli[i]+1][rowi[i]] = v.y * 0.125f;
        Qs[coli[i]+2][rowi[i]] = v.z * 0.125f;
        Qs[coli[i]+3][rowi[i]] = v.w * 0.125f;
    }
    float m[4], l[4];
    float4 Ov[4];
    #pragma unroll
    for (int qi=0;qi<4;qi++){ m[qi]=-3.0e38f; l[qi]=0.f; Ov[qi]=make_float4(0.f,0.f,0.f,0.f); }

    // prefetch K/V tile 0
    float4 kpre[4], vpre[4];
    {
        const float* base = qkv + rb*192;
        #pragma unroll
        for (int i=0;i<4;i++){
            kpre[i] = *(const float4*)(base + rowi[i]*192 + 64  + coli[i]);
            vpre[i] = *(const float4*)(base + rowi[i]*192 + 128 + coli[i]);
        }
    }
    __syncthreads();

    for (int kt2=0; kt2<64; kt2++){
        #pragma unroll
        for (int i=0;i<4;i++){
            *(float4*)&KsPs[rowi[i]][coli[i]] = kpre[i];
            *(float4*)&Vs[rowi[i]][coli[i]]   = vpre[i];
        }
        __syncthreads();
        if (kt2 < 63){
            const float* base = qkv + (rb + (kt2+1)*64)*192;
            #pragma unroll
            for (int i=0;i<4;i++){
                kpre[i] = *(const float4*)(base + rowi[i]*192 + 64  + coli[i]);
                vpre[i] = *(const float4*)(base + rowi[i]*192 + 128 + coli[i]);
            }
        }
        // S = Q·K^T  (thread: q=ty*4+qi, k=tx*4+ki)
        float sacc[4][4];
        #pragma unroll
        for (int qi=0;qi<4;qi++){ sacc[qi][0]=0.f; sacc[qi][1]=0.f; sacc[qi][2]=0.f; sacc[qi][3]=0.f; }
        #pragma unroll
        for (int d0=0; d0<64; d0+=4){
            float4 qv[4], kv[4];
            #pragma unroll
            for (int dj=0;dj<4;dj++) qv[dj] = *(const float4*)&Qs[d0+dj][ty*4];
            #pragma unroll
            for (int ki=0;ki<4;ki++) kv[ki] = *(const float4*)&KsPs[tx*4+ki][d0];
            const float* qf = (const float*)qv;
            const float* kf = (const float*)kv;
            #pragma unroll
            for (int qi=0;qi<4;qi++){
                #pragma unroll
                for (int ki=0;ki<4;ki++){
                    sacc[qi][ki] += qf[0+qi]*kf[ki*4+0] + qf[4+qi]*kf[ki*4+1]
                                  + qf[8+qi]*kf[ki*4+2] + qf[12+qi]*kf[ki*4+3];
                }
            }
        }
        // online softmax (scale folded into Q)
        float4 pw[4];
        #pragma unroll
        for (int qi=0;qi<4;qi++){
            float tm = fmaxf(fmaxf(sacc[qi][0],sacc[qi][1]), fmaxf(sacc[qi][2],sacc[qi][3]));
            tm = fmaxf(tm, __shfl_xor(tm,1));
            tm = fmaxf(tm, __shfl_xor(tm,2));
            tm = fmaxf(tm, __shfl_xor(tm,4));
            tm = fmaxf(tm, __shfl_xor(tm,8));
            float mn = fmaxf(m[qi], tm);
            float p0 = __expf(sacc[qi][0]-mn);
            float p1 = __expf(sacc[qi][1]-mn);
            float p2 = __expf(sacc[qi][2]-mn);
            float p3 = __expf(sacc[qi][3]-mn);
            float rsum = p0+p1+p2+p3;
            rsum += __shfl_xor(rsum,1);
            rsum += __shfl_xor(rsum,2);
            rsum += __shfl_xor(rsum,4);
            rsum += __shfl_xor(rsum,8);
            float al = __expf(m[qi]-mn);
            l[qi] = l[qi]*al + rsum;
            m[qi] = mn;
            Ov[qi].x*=al; Ov[qi].y*=al; Ov[qi].z*=al; Ov[qi].w*=al;
            pw[qi] = make_float4(p0,p1,p2,p3);
        }
        __syncthreads();                 // all done reading K before P overwrites it
        #pragma unroll
        for (int qi=0;qi<4;qi++)
            *(float4*)&KsPs[ty*4+qi][tx*4] = pw[qi];
        __syncthreads();
        // O += P·V  (thread: q=ty*4+qi, h=tx*4+hi; full k-sum in-thread)
        #pragma unroll
        for (int k0=0;k0<64;k0+=4){
            float4 pv[4], vv[4];
            #pragma unroll
            for (int qi=0;qi<4;qi++) pv[qi] = *(const float4*)&KsPs[ty*4+qi][k0];
            #pragma unroll
            for (int kj=0;kj<4;kj++) vv[kj] = *(const float4*)&Vs[k0+kj][tx*4];
            const float* pf=(const float*)pv;
            const float* vf=(const float*)vv;
            #pragma unroll
            for (int qi=0;qi<4;qi++){
                Ov[qi].x += pf[qi*4+0]*vf[0]  + pf[qi*4+1]*vf[4]  + pf[qi*4+2]*vf[8]  + pf[qi*4+3]*vf[12];
                Ov[qi].y += pf[qi*4+0]*vf[1]  + pf[qi*4+1]*vf[5]  + pf[qi*4+2]*vf[9]  + pf[qi*4+3]*vf[13];
                Ov[qi].z += pf[qi*4+0]*vf[2]  + pf[qi*4+1]*vf[6]  + pf[qi*4+2]*vf[10] + pf[qi*4+3]*vf[14];
                Ov[qi].w += pf[qi*4+0]*vf[3]  + pf[qi*4+1]*vf[7]  + pf[qi*4+2]*vf[11] + pf[qi*4+3]*vf[15];
            }
        }
        __syncthreads();
    }
    #pragma unroll
    for (int qi=0;qi<4;qi++){
        float inv = 1.0f / l[qi];
        float4 o = Ov[qi];
        o.x*=inv; o.y*=inv; o.z*=inv; o.w*=inv;
        *(float4*)(out + (q0 + ty*4 + qi)*64 + tx*4) = o;
    }
}

extern "C" void kernel_launch(void* const* d_in, const int* in_sizes, int n_in,
                              void* d_out, int out_size, void* d_ws, size_t ws_size,
                              hipStream_t stream) {
    const float* x  = (const float*)d_in[0];
    const float* Wk = (const float*)d_in[1];
    const float* Wq = (const float*)d_in[2];
    const float* Wv = (const float*)d_in[3];
    const float* gk = (const float*)d_in[4];
    const float* bk = (const float*)d_in[5];
    const float* gq = (const float*)d_in[6];
    const float* bq = (const float*)d_in[7];
    const float* gv = (const float*)d_in[8];
    const float* bv = (const float*)d_in[9];
    float* out = (float*)d_out;
    char* ws = (char*)d_ws;
    float* Wcat = (float*)(ws);
    float* cvec = (float*)(ws + 786432);
    float* qkv  = (float*)(ws + 1048576);

    quant_k<<<dim3(3), dim3(1024), 0, stream>>>(Wq, Wk, Wv, gq, bq, gk, bk, gv, bv, Wcat, cvec);
    lngemm_k<<<dim3(256), dim3(256), 0, stream>>>(x, Wcat, cvec, qkv);
    attn_k<<<dim3(256), dim3(256), 0, stream>>>(qkv, out);
}

// Round 3
// 767.794 us; speedup vs baseline: 1.0137x; 1.0137x over previous
//
#include <hip/hip_runtime.h>
#include <math.h>

#define LN_EPS 1e-5f

// ws layout:
//   Wcat  : [1024][192] f32 @ 0          (gamma-folded ternary weights; cols 0-63=q,64-127=k,128-191=v)
//   cvec  : [192] f32 @ 786432           (beta-folded bias)
//   qkv   : [16384][192] f32 @ 1048576   (ends 13631488)
//   Opart : [ns][16384][64] f32 @ 13631488
//   ml    : [ns][16384][2]  f32 @ 13631488 + ns*4194304

// ---------------- quantize weights + fold gamma/beta ----------------
__global__ __launch_bounds__(1024) void quant_k(
    const float* __restrict__ Wq, const float* __restrict__ Wk, const float* __restrict__ Wv,
    const float* __restrict__ gq, const float* __restrict__ bq,
    const float* __restrict__ gk, const float* __restrict__ bk,
    const float* __restrict__ gv, const float* __restrict__ bv,
    float* __restrict__ Wcat, float* __restrict__ cvec)
{
    const int br = blockIdx.x;                 // 0=q, 1=k, 2=v
    const float* W = (br==0) ? Wq : (br==1 ? Wk : Wv);
    const float* g = (br==0) ? gq : (br==1 ? gk : gv);
    const float* bb= (br==0) ? bq : (br==1 ? bk : bv);
    const int t = threadIdx.x;
    __shared__ float red[1024];
    float s = 0.f;
    #pragma unroll 4
    for (int i=0;i<64;i++) s += fabsf(W[t + 1024*i]);
    red[t] = s;
    __syncthreads();
    for (int o=512;o>0;o>>=1){ if (t<o) red[t]+=red[t+o]; __syncthreads(); }
    const float mean = red[0] * (1.0f/65536.0f);   // exact /2^16

    const float ge = g[t];
    for (int h=0; h<64; h++) {
        float w  = W[t*64+h];
        float wq = fminf(1.f, fmaxf(-1.f, rintf(w/mean)));   // round-half-even like jnp.round
        Wcat[t*192 + br*64 + h] = ge*wq;
    }
    const int h = t & 63, chunk = t >> 6;
    float cp = 0.f;
    for (int i=0;i<64;i++){
        int e = chunk*64 + i;
        float w  = W[e*64+h];
        float wq = fminf(1.f, fmaxf(-1.f, rintf(w/mean)));
        cp += bb[e]*wq;
    }
    __shared__ float cred[16][64];
    cred[chunk][h] = cp;
    __syncthreads();
    if (t < 64){
        float c = 0.f;
        #pragma unroll
        for (int i=0;i<16;i++) c += cred[i][t];
        cvec[br*64 + t] = c;
    }
}

// ---------------- fused LayerNorm + ternary QKV GEMM ----------------
__global__ __launch_bounds__(256) void lngemm_k(
    const float* __restrict__ x, const float* __restrict__ Wcat,
    const float* __restrict__ cvec, float* __restrict__ qkv)
{
    __shared__ float As[16][68];     // [k][m], padded
    __shared__ float Bs[16][192];    // [k][n]
    __shared__ float mu_s[64], rs_s[64];
    const int t  = threadIdx.x;
    const int r0 = blockIdx.x * 64;

    const int arow = t >> 2, apart = t & 3;
    const int bkk  = t >> 4, bn   = (t & 15) * 12;

    float4 aV = *(const float4*)(x + (r0 + arow)*1024 + apart*4);
    const float* wr0 = Wcat + bkk*192 + bn;
    float4 bV0 = *(const float4*)(wr0);
    float4 bV1 = *(const float4*)(wr0+4);
    float4 bV2 = *(const float4*)(wr0+8);

    {
        const float* xr = x + (r0 + arow)*1024 + apart*4;
        float s1=0.f, s2=0.f;
        #pragma unroll 8
        for (int j=0;j<64;j++){
            float4 v = *(const float4*)(xr + j*16);
            s1 += v.x+v.y+v.z+v.w;
            s2 += v.x*v.x+v.y*v.y+v.z*v.z+v.w*v.w;
        }
        s1 += __shfl_xor(s1,1); s1 += __shfl_xor(s1,2);
        s2 += __shfl_xor(s2,1); s2 += __shfl_xor(s2,2);
        if (apart==0){
            float mu  = s1*(1.f/1024.f);
            float var = s2*(1.f/1024.f) - mu*mu;
            mu_s[arow]=mu; rs_s[arow]=rsqrtf(var+LN_EPS);
        }
    }
    __syncthreads();
    const float mu = mu_s[arow], rs = rs_s[arow];

    const int tx = t & 15, ty = t >> 4;
    float4 c0 = *(const float4*)(cvec + tx*4);
    float4 c1 = *(const float4*)(cvec + tx*4 + 64);
    float4 c2 = *(const float4*)(cvec + tx*4 + 128);
    float4 acc[4][3];
    #pragma unroll
    for (int mi=0;mi<4;mi++){ acc[mi][0]=c0; acc[mi][1]=c1; acc[mi][2]=c2; }

    for (int kt=0; kt<64; kt++){
        As[apart*4+0][arow] = (aV.x-mu)*rs;
        As[apart*4+1][arow] = (aV.y-mu)*rs;
        As[apart*4+2][arow] = (aV.z-mu)*rs;
        As[apart*4+3][arow] = (aV.w-mu)*rs;
        *(float4*)&Bs[bkk][bn+0] = bV0;
        *(float4*)&Bs[bkk][bn+4] = bV1;
        *(float4*)&Bs[bkk][bn+8] = bV2;
        __syncthreads();
        if (kt < 63){
            aV = *(const float4*)(x + (r0 + arow)*1024 + (kt+1)*16 + apart*4);
            const float* wr = Wcat + ((kt+1)*16 + bkk)*192 + bn;
            bV0 = *(const float4*)(wr);
            bV1 = *(const float4*)(wr+4);
            bV2 = *(const float4*)(wr+8);
        }
        #pragma unroll
        for (int kk=0;kk<16;kk++){
            float4 a4  = *(const float4*)&As[kk][ty*4];
            float4 b40 = *(const float4*)&Bs[kk][tx*4];
            float4 b41 = *(const float4*)&Bs[kk][tx*4+64];
            float4 b42 = *(const float4*)&Bs[kk][tx*4+128];
            float am[4] = {a4.x, a4.y, a4.z, a4.w};
            #pragma unroll
            for (int mi=0;mi<4;mi++){
                acc[mi][0].x += am[mi]*b40.x; acc[mi][0].y += am[mi]*b40.y;
                acc[mi][0].z += am[mi]*b40.z; acc[mi][0].w += am[mi]*b40.w;
                acc[mi][1].x += am[mi]*b41.x; acc[mi][1].y += am[mi]*b41.y;
                acc[mi][1].z += am[mi]*b41.z; acc[mi][1].w += am[mi]*b41.w;
                acc[mi][2].x += am[mi]*b42.x; acc[mi][2].y += am[mi]*b42.y;
                acc[mi][2].z += am[mi]*b42.z; acc[mi][2].w += am[mi]*b42.w;
            }
        }
        __syncthreads();
    }
    #pragma unroll
    for (int mi=0;mi<4;mi++){
        float* outr = qkv + (r0 + ty*4 + mi)*192;
        *(float4*)(outr + tx*4)       = acc[mi][0];
        *(float4*)(outr + tx*4 + 64)  = acc[mi][1];
        *(float4*)(outr + tx*4 + 128) = acc[mi][2];
    }
}

// ---------------- split-K flash attention (fp32) ----------------
// grid = 256*ns blocks; virt id = ks*256 + b*64 + qt; each block does tps=64/ns k-tiles.
// K stored XOR-swizzled in LDS: float4 (row,c) at col c ^ (((row>>2)&15)<<2).
__global__ __launch_bounds__(256) void attn_split_k(
    const float* __restrict__ qkv, float* __restrict__ Opart,
    float* __restrict__ ml, int tps)
{
    __shared__ float Qs[64][64];     // [d][q], pre-scaled by 1/8
    __shared__ float KsPs[64][68];   // K swizzled [k][d-swz]; reused as P[q][k]
    __shared__ float Vs[64][64];     // [k][h]
    const int t  = threadIdx.x;
    const int tx = t & 15, ty = t >> 4;
    const int bid = blockIdx.x, nwg = gridDim.x;
    const int virt = (bid & 7) * (nwg >> 3) + (bid >> 3);   // XCD-contiguous chunks
    const int ks = virt >> 8;
    const int b  = (virt >> 6) & 3;
    const int qt = virt & 63;
    const int rb = b * 4096;
    const int q0 = rb + qt * 64;
    const int kt0 = ks * tps;

    int rowi[4], coli[4];
    #pragma unroll
    for (int i=0;i<4;i++){
        int f4 = t + 256*i;
        rowi[i] = f4 >> 4;
        coli[i] = (f4 & 15) * 4;
    }
    #pragma unroll
    for (int i=0;i<4;i++){
        float4 v = *(const float4*)(qkv + (q0 + rowi[i])*192 + coli[i]);
        Qs[coli[i]+0][rowi[i]] = v.x * 0.125f;
        Qs[coli[i]+1][rowi[i]] = v.y * 0.125f;
        Qs[coli[i]+2][rowi[i]] = v.z * 0.125f;
        Qs[coli[i]+3][rowi[i]] = v.w * 0.125f;
    }
    float m[4], l[4];
    float4 Ov[4];
    #pragma unroll
    for (int qi=0;qi<4;qi++){ m[qi]=-3.0e38f; l[qi]=0.f; Ov[qi]=make_float4(0.f,0.f,0.f,0.f); }

    float4 kpre[4], vpre[4];
    {
        const float* base = qkv + (rb + kt0*64)*192;
        #pragma unroll
        for (int i=0;i<4;i++){
            kpre[i] = *(const float4*)(base + rowi[i]*192 + 64  + coli[i]);
            vpre[i] = *(const float4*)(base + rowi[i]*192 + 128 + coli[i]);
        }
    }
    __syncthreads();

    for (int kt2=kt0; kt2<kt0+tps; kt2++){
        #pragma unroll
        for (int i=0;i<4;i++){
            int sw = coli[i] ^ (((rowi[i]>>2)&15)<<2);
            *(float4*)&KsPs[rowi[i]][sw] = kpre[i];
            *(float4*)&Vs[rowi[i]][coli[i]] = vpre[i];
        }
        __syncthreads();
        if (kt2 < kt0+tps-1){
            const float* base = qkv + (rb + (kt2+1)*64)*192;
            #pragma unroll
            for (int i=0;i<4;i++){
                kpre[i] = *(const float4*)(base + rowi[i]*192 + 64  + coli[i]);
                vpre[i] = *(const float4*)(base + rowi[i]*192 + 128 + coli[i]);
            }
        }
        // S = Q.K^T  (thread: q=ty*4+qi, k=tx*4+ki); K read de-swizzled: col = d0 ^ (tx<<2)
        float sacc[4][4];
        #pragma unroll
        for (int qi=0;qi<4;qi++){ sacc[qi][0]=0.f; sacc[qi][1]=0.f; sacc[qi][2]=0.f; sacc[qi][3]=0.f; }
        #pragma unroll
        for (int d0=0; d0<64; d0+=4){
            float4 qv[4], kv[4];
            #pragma unroll
            for (int dj=0;dj<4;dj++) qv[dj] = *(const float4*)&Qs[d0+dj][ty*4];
            #pragma unroll
            for (int ki=0;ki<4;ki++) kv[ki] = *(const float4*)&KsPs[tx*4+ki][d0 ^ (tx<<2)];
            const float* qf = (const float*)qv;
            const float* kf = (const float*)kv;
            #pragma unroll
            for (int qi=0;qi<4;qi++){
                #pragma unroll
                for (int ki=0;ki<4;ki++){
                    sacc[qi][ki] += qf[0+qi]*kf[ki*4+0] + qf[4+qi]*kf[ki*4+1]
                                  + qf[8+qi]*kf[ki*4+2] + qf[12+qi]*kf[ki*4+3];
                }
            }
        }
        float4 pw[4];
        #pragma unroll
        for (int qi=0;qi<4;qi++){
            float tm = fmaxf(fmaxf(sacc[qi][0],sacc[qi][1]), fmaxf(sacc[qi][2],sacc[qi][3]));
            tm = fmaxf(tm, __shfl_xor(tm,1));
            tm = fmaxf(tm, __shfl_xor(tm,2));
            tm = fmaxf(tm, __shfl_xor(tm,4));
            tm = fmaxf(tm, __shfl_xor(tm,8));
            float mn = fmaxf(m[qi], tm);
            float p0 = __expf(sacc[qi][0]-mn);
            float p1 = __expf(sacc[qi][1]-mn);
            float p2 = __expf(sacc[qi][2]-mn);
            float p3 = __expf(sacc[qi][3]-mn);
            float rsum = p0+p1+p2+p3;
            rsum += __shfl_xor(rsum,1);
            rsum += __shfl_xor(rsum,2);
            rsum += __shfl_xor(rsum,4);
            rsum += __shfl_xor(rsum,8);
            float al = __expf(m[qi]-mn);
            l[qi] = l[qi]*al + rsum;
            m[qi] = mn;
            Ov[qi].x*=al; Ov[qi].y*=al; Ov[qi].z*=al; Ov[qi].w*=al;
            pw[qi] = make_float4(p0,p1,p2,p3);
        }
        __syncthreads();
        #pragma unroll
        for (int qi=0;qi<4;qi++)
            *(float4*)&KsPs[ty*4+qi][tx*4] = pw[qi];
        __syncthreads();
        #pragma unroll
        for (int k0=0;k0<64;k0+=4){
            float4 pv[4], vv[4];
            #pragma unroll
            for (int qi=0;qi<4;qi++) pv[qi] = *(const float4*)&KsPs[ty*4+qi][k0];
            #pragma unroll
            for (int kj=0;kj<4;kj++) vv[kj] = *(const float4*)&Vs[k0+kj][tx*4];
            const float* pf=(const float*)pv;
            const float* vf=(const float*)vv;
            #pragma unroll
            for (int qi=0;qi<4;qi++){
                Ov[qi].x += pf[qi*4+0]*vf[0]  + pf[qi*4+1]*vf[4]  + pf[qi*4+2]*vf[8]  + pf[qi*4+3]*vf[12];
                Ov[qi].y += pf[qi*4+0]*vf[1]  + pf[qi*4+1]*vf[5]  + pf[qi*4+2]*vf[9]  + pf[qi*4+3]*vf[13];
                Ov[qi].z += pf[qi*4+0]*vf[2]  + pf[qi*4+1]*vf[6]  + pf[qi*4+2]*vf[10] + pf[qi*4+3]*vf[14];
                Ov[qi].w += pf[qi*4+0]*vf[3]  + pf[qi*4+1]*vf[7]  + pf[qi*4+2]*vf[11] + pf[qi*4+3]*vf[15];
            }
        }
        __syncthreads();
    }
    // write unnormalized partials + (m,l)
    const int ksplit = ks;
    #pragma unroll
    for (int qi=0;qi<4;qi++){
        int row = q0 + ty*4 + qi;
        *(float4*)(Opart + ((size_t)ksplit*16384 + row)*64 + tx*4) = Ov[qi];
        if (tx == 0){
            ml[((size_t)ksplit*16384 + row)*2 + 0] = m[qi];
            ml[((size_t)ksplit*16384 + row)*2 + 1] = l[qi];
        }
    }
}

// ---------------- combine split-K partials ----------------
__global__ __launch_bounds__(256) void combine_k(
    const float* __restrict__ Opart, const float* __restrict__ ml,
    float* __restrict__ out, int nsplit)
{
    const int t = threadIdx.x;
    const int tx = t & 15, ty = t >> 4;
    const int r = blockIdx.x * 16 + ty;
    float mstar = -3.0e38f;
    for (int s=0;s<nsplit;s++)
        mstar = fmaxf(mstar, ml[((size_t)s*16384 + r)*2]);
    float lstar = 0.f;
    float4 o = make_float4(0.f,0.f,0.f,0.f);
    for (int s=0;s<nsplit;s++){
        float ms = ml[((size_t)s*16384 + r)*2];
        float ls = ml[((size_t)s*16384 + r)*2 + 1];
        float w  = __expf(ms - mstar);
        lstar += w * ls;
        float4 p = *(const float4*)(Opart + ((size_t)s*16384 + r)*64 + tx*4);
        o.x += w*p.x; o.y += w*p.y; o.z += w*p.z; o.w += w*p.w;
    }
    float inv = 1.0f / lstar;
    o.x*=inv; o.y*=inv; o.z*=inv; o.w*=inv;
    *(float4*)(out + (size_t)r*64 + tx*4) = o;
}

extern "C" void kernel_launch(void* const* d_in, const int* in_sizes, int n_in,
                              void* d_out, int out_size, void* d_ws, size_t ws_size,
                              hipStream_t stream) {
    const float* x  = (const float*)d_in[0];
    const float* Wk = (const float*)d_in[1];
    const float* Wq = (const float*)d_in[2];
    const float* Wv = (const float*)d_in[3];
    const float* gk = (const float*)d_in[4];
    const float* bk = (const float*)d_in[5];
    const float* gq = (const float*)d_in[6];
    const float* bq = (const float*)d_in[7];
    const float* gv = (const float*)d_in[8];
    const float* bv = (const float*)d_in[9];
    float* out = (float*)d_out;
    char* ws = (char*)d_ws;
    float* Wcat = (float*)(ws);
    float* cvec = (float*)(ws + 786432);
    float* qkv  = (float*)(ws + 1048576);

    const size_t base = 13631488;   // end of qkv
    int ns;
    if      (ws_size >= base + 4ull*4325376) ns = 4;
    else if (ws_size >= base + 2ull*4325376) ns = 2;
    else                                     ns = 1;
    float* Opart = (float*)(ws + base);
    float* mlp   = (float*)(ws + base + (size_t)ns*4194304);

    quant_k<<<dim3(3), dim3(1024), 0, stream>>>(Wq, Wk, Wv, gq, bq, gk, bk, gv, bv, Wcat, cvec);
    lngemm_k<<<dim3(256), dim3(256), 0, stream>>>(x, Wcat, cvec, qkv);
    attn_split_k<<<dim3(256*ns), dim3(256), 0, stream>>>(qkv, Opart, mlp, 64/ns);
    combine_k<<<dim3(1024), dim3(256), 0, stream>>>(Opart, mlp, out, ns);
}

// Round 4
// 360.589 us; speedup vs baseline: 2.1585x; 2.1293x over previous
//
#include <hip/hip_runtime.h>
#include <math.h>

#define LN_EPS 1e-5f

typedef __attribute__((ext_vector_type(8))) short    bf16x8;
typedef __attribute__((ext_vector_type(8))) _Float16 f16x8;
typedef __attribute__((ext_vector_type(4))) float    f32x4;

__device__ inline ushort f2bf(float f){           // RNE f32->bf16
    union { float f; uint u; } v; v.f = f;
    uint r = v.u + 0x7fffu + ((v.u >> 16) & 1u);
    return (ushort)(r >> 16);
}
__device__ inline float bf2f(ushort h){
    union { uint u; float f; } v; v.u = ((uint)h) << 16;
    return v.f;
}
__device__ inline ushort f2h(float f){            // f32->f16 bits
    union { _Float16 h; ushort u; } v; v.h = (_Float16)f;
    return v.u;
}

// ws layout (bytes):
//   Wcat [1024][192] f32 @ 0
//   cvec [192] f32       @ 786432
//   qf   [16384][64] f32 @ 1048576   (-> 5242880)
//   khi  [16384][64] bf16 @ 5242880  (-> 7340032)
//   klo  [16384][64] f16  @ 7340032  (-> 9437184)
//   vthi [4][64][4096] bf16 @ 9437184  (-> 11534336)   (per-batch V^T)
//   vtlo [4][64][4096] bf16 @ 11534336 (-> 13631488)
//   Opart [ns][16384][64] f32 @ 13631488
//   ml    [ns][16384][2]  f32 @ 13631488 + ns*4194304

// ---------------- quantize weights + fold gamma/beta ----------------
__global__ __launch_bounds__(1024) void quant_k(
    const float* __restrict__ Wq, const float* __restrict__ Wk, const float* __restrict__ Wv,
    const float* __restrict__ gq, const float* __restrict__ bq,
    const float* __restrict__ gk, const float* __restrict__ bk,
    const float* __restrict__ gv, const float* __restrict__ bv,
    float* __restrict__ Wcat, float* __restrict__ cvec)
{
    const int br = blockIdx.x;                 // 0=q, 1=k, 2=v
    const float* W = (br==0) ? Wq : (br==1 ? Wk : Wv);
    const float* g = (br==0) ? gq : (br==1 ? gk : gv);
    const float* bb= (br==0) ? bq : (br==1 ? bk : bv);
    const int t = threadIdx.x;
    __shared__ float red[1024];
    float s = 0.f;
    #pragma unroll 4
    for (int i=0;i<64;i++) s += fabsf(W[t + 1024*i]);
    red[t] = s;
    __syncthreads();
    for (int o=512;o>0;o>>=1){ if (t<o) red[t]+=red[t+o]; __syncthreads(); }
    const float mean = red[0] * (1.0f/65536.0f);   // exact /2^16

    const float ge = g[t];
    for (int h=0; h<64; h++) {
        float w  = W[t*64+h];
        float wq = fminf(1.f, fmaxf(-1.f, rintf(w/mean)));   // round-half-even like jnp.round
        Wcat[t*192 + br*64 + h] = ge*wq;
    }
    const int h = t & 63, chunk = t >> 6;
    float cp = 0.f;
    for (int i=0;i<64;i++){
        int e = chunk*64 + i;
        float w  = W[e*64+h];
        float wq = fminf(1.f, fmaxf(-1.f, rintf(w/mean)));
        cp += bb[e]*wq;
    }
    __shared__ float cred[16][64];
    cred[chunk][h] = cp;
    __syncthreads();
    if (t < 64){
        float c = 0.f;
        #pragma unroll
        for (int i=0;i<16;i++) c += cred[i][t];
        cvec[br*64 + t] = c;
    }
}

// ---------------- fused LayerNorm + ternary QKV GEMM ----------------
// Writes: qf fp32; khi bf16 + klo f16 (exact hi/lo split); vthi/vtlo bf16 (V^T per batch).
__global__ __launch_bounds__(256) void lngemm_k(
    const float* __restrict__ x, const float* __restrict__ Wcat,
    const float* __restrict__ cvec, float* __restrict__ qf,
    ushort* __restrict__ khi, ushort* __restrict__ klo,
    ushort* __restrict__ vthi, ushort* __restrict__ vtlo)
{
    __shared__ float As[16][68];     // [k][m], padded
    __shared__ float Bs[16][192];    // [k][n]
    __shared__ float mu_s[64], rs_s[64];
    const int t  = threadIdx.x;
    const int r0 = blockIdx.x * 64;

    const int arow = t >> 2, apart = t & 3;
    const int bkk  = t >> 4, bn   = (t & 15) * 12;

    float4 aV = *(const float4*)(x + (r0 + arow)*1024 + apart*4);
    const float* wr0 = Wcat + bkk*192 + bn;
    float4 bV0 = *(const float4*)(wr0);
    float4 bV1 = *(const float4*)(wr0+4);
    float4 bV2 = *(const float4*)(wr0+8);

    {
        const float* xr = x + (r0 + arow)*1024 + apart*4;
        float s1=0.f, s2=0.f;
        #pragma unroll 8
        for (int j=0;j<64;j++){
            float4 v = *(const float4*)(xr + j*16);
            s1 += v.x+v.y+v.z+v.w;
            s2 += v.x*v.x+v.y*v.y+v.z*v.z+v.w*v.w;
        }
        s1 += __shfl_xor(s1,1); s1 += __shfl_xor(s1,2);
        s2 += __shfl_xor(s2,1); s2 += __shfl_xor(s2,2);
        if (apart==0){
            float mu  = s1*(1.f/1024.f);
            float var = s2*(1.f/1024.f) - mu*mu;
            mu_s[arow]=mu; rs_s[arow]=rsqrtf(var+LN_EPS);
        }
    }
    __syncthreads();
    const float mu = mu_s[arow], rs = rs_s[arow];

    const int tx = t & 15, ty = t >> 4;
    float4 c0 = *(const float4*)(cvec + tx*4);
    float4 c1 = *(const float4*)(cvec + tx*4 + 64);
    float4 c2 = *(const float4*)(cvec + tx*4 + 128);
    float4 acc[4][3];
    #pragma unroll
    for (int mi=0;mi<4;mi++){ acc[mi][0]=c0; acc[mi][1]=c1; acc[mi][2]=c2; }

    for (int kt=0; kt<64; kt++){
        As[apart*4+0][arow] = (aV.x-mu)*rs;
        As[apart*4+1][arow] = (aV.y-mu)*rs;
        As[apart*4+2][arow] = (aV.z-mu)*rs;
        As[apart*4+3][arow] = (aV.w-mu)*rs;
        *(float4*)&Bs[bkk][bn+0] = bV0;
        *(float4*)&Bs[bkk][bn+4] = bV1;
        *(float4*)&Bs[bkk][bn+8] = bV2;
        __syncthreads();
        if (kt < 63){
            aV = *(const float4*)(x + (r0 + arow)*1024 + (kt+1)*16 + apart*4);
            const float* wr = Wcat + ((kt+1)*16 + bkk)*192 + bn;
            bV0 = *(const float4*)(wr);
            bV1 = *(const float4*)(wr+4);
            bV2 = *(const float4*)(wr+8);
        }
        #pragma unroll
        for (int kk=0;kk<16;kk++){
            float4 a4  = *(const float4*)&As[kk][ty*4];
            float4 b40 = *(const float4*)&Bs[kk][tx*4];
            float4 b41 = *(const float4*)&Bs[kk][tx*4+64];
            float4 b42 = *(const float4*)&Bs[kk][tx*4+128];
            float am[4] = {a4.x, a4.y, a4.z, a4.w};
            #pragma unroll
            for (int mi=0;mi<4;mi++){
                acc[mi][0].x += am[mi]*b40.x; acc[mi][0].y += am[mi]*b40.y;
                acc[mi][0].z += am[mi]*b40.z; acc[mi][0].w += am[mi]*b40.w;
                acc[mi][1].x += am[mi]*b41.x; acc[mi][1].y += am[mi]*b41.y;
                acc[mi][1].z += am[mi]*b41.z; acc[mi][1].w += am[mi]*b41.w;
                acc[mi][2].x += am[mi]*b42.x; acc[mi][2].y += am[mi]*b42.y;
                acc[mi][2].z += am[mi]*b42.z; acc[mi][2].w += am[mi]*b42.w;
            }
        }
        __syncthreads();
    }
    #pragma unroll
    for (int mi=0;mi<4;mi++){
        const int grow = r0 + ty*4 + mi;
        // q: fp32
        *(float4*)(qf + grow*64 + tx*4) = acc[mi][0];
        // k: hi bf16 + lo f16 (exact residual)
        float kf[4] = {acc[mi][1].x, acc[mi][1].y, acc[mi][1].z, acc[mi][1].w};
        uint2 uh, ul;
        {
            ushort h0=f2bf(kf[0]), h1=f2bf(kf[1]), h2=f2bf(kf[2]), h3=f2bf(kf[3]);
            ushort l0=f2h(kf[0]-bf2f(h0)), l1=f2h(kf[1]-bf2f(h1));
            ushort l2=f2h(kf[2]-bf2f(h2)), l3=f2h(kf[3]-bf2f(h3));
            uh.x = (uint)h0 | ((uint)h1<<16); uh.y = (uint)h2 | ((uint)h3<<16);
            ul.x = (uint)l0 | ((uint)l1<<16); ul.y = (uint)l2 | ((uint)l3<<16);
        }
        *(uint2*)(khi + (size_t)grow*64 + tx*4) = uh;
        *(uint2*)(klo + (size_t)grow*64 + tx*4) = ul;
        // v: transposed, hi/lo bf16
        float vf[4] = {acc[mi][2].x, acc[mi][2].y, acc[mi][2].z, acc[mi][2].w};
        const int bb2 = grow >> 12, tt = grow & 4095;
        #pragma unroll
        for (int c=0;c<4;c++){
            int h = tx*4 + c;
            ushort hb = f2bf(vf[c]);
            vthi[((size_t)bb2*64 + h)*4096 + tt] = hb;
            vtlo[((size_t)bb2*64 + h)*4096 + tt] = f2bf(vf[c] - bf2f(hb));
        }
    }
}

// ---------------- split-K flash attention, MFMA hi/lo ----------------
// grid = 256*ns; virt = ks*256 + b*64 + qt. 4 waves, each owns 16 q-rows.
// LDS 32 KB: Khi(8K bf16) | Klo(8K f16) | Vhi(8K bf16) | Vlo(8K bf16);
// P (u32-packed bf16 hi/lo) aliases K region per wave after S-phase.
// All LDS rows are 128 B with 16B-granule XOR swizzle ^((row&7)<<4).
__global__ __launch_bounds__(256, 2) void attn_mfma_k(
    const float* __restrict__ qf, const ushort* __restrict__ khi,
    const ushort* __restrict__ klo, const ushort* __restrict__ vthi,
    const ushort* __restrict__ vtlo, float* __restrict__ Opart,
    float* __restrict__ ml, int tps)
{
    __shared__ char smem[32768];

    const int t    = threadIdx.x;
    const int lane = t & 63;
    const int w    = t >> 6;
    const int lr   = lane & 15;
    const int lq   = lane >> 4;

    const int bid = blockIdx.x, nwg = gridDim.x;
    const int virt = (bid & 7) * (nwg >> 3) + (bid >> 3);   // XCD-contiguous (nwg%8==0)
    const int ks = virt >> 8;
    const int b  = (virt >> 6) & 3;
    const int qt = virt & 63;

    // ---- Q fragments in registers (scale 1/8 folded; hi bf16, hi f16, lo f16) ----
    const int gq = b*4096 + qt*64 + w*16 + lr;
    bf16x8 aqh[2]; f16x8 aqh16[2], aql16[2];
    #pragma unroll
    for (int ks2=0; ks2<2; ks2++){
        const float* qp = qf + (size_t)gq*64 + ks2*32 + lq*8;
        float4 qa = *(const float4*)(qp);
        float4 qb = *(const float4*)(qp+4);
        float qv[8] = {qa.x,qa.y,qa.z,qa.w,qb.x,qb.y,qb.z,qb.w};
        #pragma unroll
        for (int j=0;j<8;j++){
            float q = qv[j] * 0.125f;
            ushort hb = f2bf(q);
            float  hf = bf2f(hb);
            aqh[ks2][j]   = (short)hb;
            aqh16[ks2][j] = (_Float16)hf;      // exact (bf16 fits f16 mantissa)
            aql16[ks2][j] = (_Float16)(q - hf);
        }
    }

    float m_[4], l_[4];
    f32x4 Oacc[4];
    #pragma unroll
    for (int i=0;i<4;i++){ m_[i] = -3.0e38f; l_[i] = 0.f; }
    #pragma unroll
    for (int n=0;n<4;n++) Oacc[n] = (f32x4){0.f,0.f,0.f,0.f};

    const int srow = t >> 2;             // staging: LDS row 0..63
    const int sseg = (t & 3) * 32;       // byte seg within 128B row
    const int sd0 = srow*128 + (sseg ^ ((srow&7)<<4));
    const int sd1 = srow*128 + ((sseg+16) ^ ((srow&7)<<4));

    for (int kt = ks*tps; kt < ks*tps + tps; kt++){
        __syncthreads();   // prior iter fully done with K(=P)/V
        {
            const int grow = b*4096 + kt*64 + srow;
            const char* skh = (const char*)(khi + (size_t)grow*64) + sseg;
            const char* skl = (const char*)(klo + (size_t)grow*64) + sseg;
            const char* svh = (const char*)(vthi + ((size_t)b*64 + srow)*4096 + kt*64) + sseg;
            const char* svl = (const char*)(vtlo + ((size_t)b*64 + srow)*4096 + kt*64) + sseg;
            *(uint4*)(smem         + sd0) = *(const uint4*)(skh);
            *(uint4*)(smem         + sd1) = *(const uint4*)(skh+16);
            *(uint4*)(smem +  8192 + sd0) = *(const uint4*)(skl);
            *(uint4*)(smem +  8192 + sd1) = *(const uint4*)(skl+16);
            *(uint4*)(smem + 16384 + sd0) = *(const uint4*)(svh);
            *(uint4*)(smem + 16384 + sd1) = *(const uint4*)(svh+16);
            *(uint4*)(smem + 24576 + sd0) = *(const uint4*)(svl);
            *(uint4*)(smem + 24576 + sd1) = *(const uint4*)(svl+16);
        }
        __syncthreads();

        // ---- S = Q·K^T : 4 split terms, f32 accumulation ----
        f32x4 sacc[4];
        #pragma unroll
        for (int n=0;n<4;n++) sacc[n] = (f32x4){0.f,0.f,0.f,0.f};
        #pragma unroll
        for (int ks2=0; ks2<2; ks2++){
            #pragma unroll
            for (int n=0;n<4;n++){
                const int row = n*16 + lr;
                const int bc  = (ks2*32 + lq*8)*2;
                const int off = row*128 + (bc ^ ((row&7)<<4));
                bf16x8 bkh = *(const bf16x8*)(smem + off);
                f16x8  bkl = *(const f16x8*)(smem + 8192 + off);
                f16x8  bkh16;
                #pragma unroll
                for (int j=0;j<8;j++) bkh16[j] = (_Float16)bf2f((ushort)bkh[j]);
                sacc[n] = __builtin_amdgcn_mfma_f32_16x16x32_bf16(aqh[ks2],  bkh,   sacc[n], 0,0,0);
                sacc[n] = __builtin_amdgcn_mfma_f32_16x16x32_f16 (aqh16[ks2], bkl,  sacc[n], 0,0,0);
                sacc[n] = __builtin_amdgcn_mfma_f32_16x16x32_f16 (aql16[ks2], bkh16,sacc[n], 0,0,0);
                sacc[n] = __builtin_amdgcn_mfma_f32_16x16x32_f16 (aql16[ks2], bkl,  sacc[n], 0,0,0);
            }
        }

        // ---- online softmax (C-layout: row=(lq*4+i), col=lr+16n) ----
        float pvals[4][4];
        float al[4];
        #pragma unroll
        for (int i=0;i<4;i++){
            float tm = fmaxf(fmaxf(sacc[0][i],sacc[1][i]), fmaxf(sacc[2][i],sacc[3][i]));
            tm = fmaxf(tm, __shfl_xor(tm,1));
            tm = fmaxf(tm, __shfl_xor(tm,2));
            tm = fmaxf(tm, __shfl_xor(tm,4));
            tm = fmaxf(tm, __shfl_xor(tm,8));
            float mn = fmaxf(m_[i], tm);
            float a  = __expf(m_[i] - mn);
            float rs = 0.f;
            #pragma unroll
            for (int n=0;n<4;n++){
                float p = __expf(sacc[n][i] - mn);
                pvals[n][i] = p;
                rs += p;
            }
            rs += __shfl_xor(rs,1);
            rs += __shfl_xor(rs,2);
            rs += __shfl_xor(rs,4);
            rs += __shfl_xor(rs,8);
            l_[i] = l_[i]*a + rs;
            m_[i] = mn;
            al[i] = a;
        }
        #pragma unroll
        for (int n=0;n<4;n++){
            #pragma unroll
            for (int i=0;i<4;i++) Oacc[n][i] *= al[i];
        }

        // ---- P -> LDS (aliases K region; all waves done reading K first) ----
        __syncthreads();
        char* Pw = smem + w*4096;     // [16 rows][64 u32], 256B rows, same swizzle
        #pragma unroll
        for (int n=0;n<4;n++){
            #pragma unroll
            for (int i=0;i<4;i++){
                const int row = lq*4 + i;
                const int bc  = (n*16 + lr)*4;
                float  p  = pvals[n][i];
                ushort ph = f2bf(p);
                ushort pl = f2bf(p - bf2f(ph));
                *(uint*)(Pw + row*256 + (bc ^ ((row&7)<<4))) = (uint)ph | ((uint)pl << 16);
            }
        }
        asm volatile("s_waitcnt lgkmcnt(0)" ::: "memory");   // own-wave P writes visible

        // ---- O += P·V : 3 split terms ----
        #pragma unroll
        for (int ks2=0; ks2<2; ks2++){
            const int pbc = ks2*128 + lq*32;
            uint4 pv0 = *(const uint4*)(Pw + lr*256 + ( pbc      ^ ((lr&7)<<4)));
            uint4 pv1 = *(const uint4*)(Pw + lr*256 + ((pbc+16)  ^ ((lr&7)<<4)));
            uint pu[8] = {pv0.x,pv0.y,pv0.z,pv0.w,pv1.x,pv1.y,pv1.z,pv1.w};
            bf16x8 ph, pl;
            #pragma unroll
            for (int j=0;j<8;j++){
                ph[j] = (short)(pu[j] & 0xffffu);
                pl[j] = (short)(pu[j] >> 16);
            }
            #pragma unroll
            for (int n=0;n<4;n++){
                const int row = n*16 + lr;
                const int bc  = (ks2*32 + lq*8)*2;
                const int off = row*128 + (bc ^ ((row&7)<<4));
                bf16x8 bvh = *(const bf16x8*)(smem + 16384 + off);
                bf16x8 bvl = *(const bf16x8*)(smem + 24576 + off);
                Oacc[n] = __builtin_amdgcn_mfma_f32_16x16x32_bf16(ph, bvh, Oacc[n], 0,0,0);
                Oacc[n] = __builtin_amdgcn_mfma_f32_16x16x32_bf16(ph, bvl, Oacc[n], 0,0,0);
                Oacc[n] = __builtin_amdgcn_mfma_f32_16x16x32_bf16(pl, bvh, Oacc[n], 0,0,0);
            }
        }
    }

    // ---- epilogue: unnormalized partials + (m,l) ----
    #pragma unroll
    for (int n=0;n<4;n++){
        #pragma unroll
        for (int i=0;i<4;i++){
            const int row = b*4096 + qt*64 + w*16 + lq*4 + i;
            Opart[((size_t)ks*16384 + row)*64 + n*16 + lr] = Oacc[n][i];
        }
    }
    if (lr == 0){
        #pragma unroll
        for (int i=0;i<4;i++){
            const int row = b*4096 + qt*64 + w*16 + lq*4 + i;
            ml[((size_t)ks*16384 + row)*2 + 0] = m_[i];
            ml[((size_t)ks*16384 + row)*2 + 1] = l_[i];
        }
    }
}

// ---------------- combine split-K partials ----------------
__global__ __launch_bounds__(256) void combine_k(
    const float* __restrict__ Opart, const float* __restrict__ ml,
    float* __restrict__ out, int nsplit)
{
    const int t = threadIdx.x;
    const int tx = t & 15, ty = t >> 4;
    const int r = blockIdx.x * 16 + ty;
    float mstar = -3.0e38f;
    for (int s=0;s<nsplit;s++)
        mstar = fmaxf(mstar, ml[((size_t)s*16384 + r)*2]);
    float lstar = 0.f;
    float4 o = make_float4(0.f,0.f,0.f,0.f);
    for (int s=0;s<nsplit;s++){
        float ms = ml[((size_t)s*16384 + r)*2];
        float ls = ml[((size_t)s*16384 + r)*2 + 1];
        float wgt = __expf(ms - mstar);
        lstar += wgt * ls;
        float4 p = *(const float4*)(Opart + ((size_t)s*16384 + r)*64 + tx*4);
        o.x += wgt*p.x; o.y += wgt*p.y; o.z += wgt*p.z; o.w += wgt*p.w;
    }
    float inv = 1.0f / lstar;
    o.x*=inv; o.y*=inv; o.z*=inv; o.w*=inv;
    *(float4*)(out + (size_t)r*64 + tx*4) = o;
}

extern "C" void kernel_launch(void* const* d_in, const int* in_sizes, int n_in,
                              void* d_out, int out_size, void* d_ws, size_t ws_size,
                              hipStream_t stream) {
    const float* x  = (const float*)d_in[0];
    const float* Wk = (const float*)d_in[1];
    const float* Wq = (const float*)d_in[2];
    const float* Wv = (const float*)d_in[3];
    const float* gk = (const float*)d_in[4];
    const float* bk = (const float*)d_in[5];
    const float* gq = (const float*)d_in[6];
    const float* bq = (const float*)d_in[7];
    const float* gv = (const float*)d_in[8];
    const float* bv = (const float*)d_in[9];
    float* out = (float*)d_out;
    char* ws = (char*)d_ws;
    float*  Wcat = (float*)(ws);
    float*  cvec = (float*)(ws + 786432);
    float*  qf   = (float*)(ws + 1048576);
    ushort* khi  = (ushort*)(ws + 5242880);
    ushort* klo  = (ushort*)(ws + 7340032);
    ushort* vthi = (ushort*)(ws + 9437184);
    ushort* vtlo = (ushort*)(ws + 11534336);

    const size_t base = 13631488;
    int ns;
    if      (ws_size >= base + 4ull*4325376) ns = 4;
    else if (ws_size >= base + 2ull*4325376) ns = 2;
    else                                     ns = 1;
    float* Opart = (float*)(ws + base);
    float* mlp   = (float*)(ws + base + (size_t)ns*4194304);

    quant_k<<<dim3(3), dim3(1024), 0, stream>>>(Wq, Wk, Wv, gq, bq, gk, bk, gv, bv, Wcat, cvec);
    lngemm_k<<<dim3(256), dim3(256), 0, stream>>>(x, Wcat, cvec, qf, khi, klo, vthi, vtlo);
    attn_mfma_k<<<dim3(256*ns), dim3(256), 0, stream>>>(qf, khi, klo, vthi, vtlo, Opart, mlp, 64/ns);
    combine_k<<<dim3(1024), dim3(256), 0, stream>>>(Opart, mlp, out, ns);
}

// Round 5
// 325.973 us; speedup vs baseline: 2.3877x; 1.1062x over previous
//
#include <hip/hip_runtime.h>
#include <math.h>

#define LN_EPS 1e-5f

typedef __attribute__((ext_vector_type(8))) short    bf16x8;
typedef __attribute__((ext_vector_type(8))) _Float16 f16x8;
typedef __attribute__((ext_vector_type(4))) float    f32x4;

__device__ inline ushort f2bf(float f){           // RNE f32->bf16
    union { float f; uint u; } v; v.f = f;
    uint r = v.u + 0x7fffu + ((v.u >> 16) & 1u);
    return (ushort)(r >> 16);
}
__device__ inline float bf2f(ushort h){
    union { uint u; float f; } v; v.u = ((uint)h) << 16;
    return v.f;
}
__device__ inline ushort f2h(float f){            // f32->f16 bits
    union { _Float16 h; ushort u; } v; v.h = (_Float16)f;
    return v.u;
}

// ws layout (bytes):
//   Wg_hi [192][1024] bf16 @ 0        (transposed gamma*ternary, hi)
//   Wg_lo [192][1024] bf16 @ 393216   (residual)
//   colsumg [192] f32 @ 786432        (sum_e gamma*wq)
//   cvec    [192] f32 @ 787200        (sum_e beta*wq)
//   qf   [16384][64] f32 @ 1048576   (-> 5242880)
//   khi  [16384][64] bf16 @ 5242880
//   klo  [16384][64] f16  @ 7340032
//   vthi [4][64][4096] bf16 @ 9437184
//   vtlo [4][64][4096] bf16 @ 11534336
//   Opart [ns][16384][64] f32 @ 13631488
//   ml    [ns][16384][2]  f32 @ 13631488 + ns*4194304

// ---------------- quantize weights: Wg=gamma*tern (hi/lo bf16, transposed) ----------------
__global__ __launch_bounds__(1024) void quant_k(
    const float* __restrict__ Wq, const float* __restrict__ Wk, const float* __restrict__ Wv,
    const float* __restrict__ gq, const float* __restrict__ bq,
    const float* __restrict__ gk, const float* __restrict__ bk,
    const float* __restrict__ gv, const float* __restrict__ bv,
    ushort* __restrict__ Wg_hi, ushort* __restrict__ Wg_lo,
    float* __restrict__ colsumg, float* __restrict__ cvec)
{
    const int br = blockIdx.x;                 // 0=q, 1=k, 2=v
    const float* W = (br==0) ? Wq : (br==1 ? Wk : Wv);
    const float* g = (br==0) ? gq : (br==1 ? gk : gv);
    const float* bb= (br==0) ? bq : (br==1 ? bk : bv);
    const int t = threadIdx.x;
    __shared__ float red[1024];
    float s = 0.f;
    #pragma unroll 4
    for (int i=0;i<64;i++) s += fabsf(W[t + 1024*i]);
    red[t] = s;
    __syncthreads();
    for (int o=512;o>0;o>>=1){ if (t<o) red[t]+=red[t+o]; __syncthreads(); }
    const float mean = red[0] * (1.0f/65536.0f);   // exact /2^16

    const float ge = g[t];
    for (int h=0; h<64; h++) {
        float w  = W[t*64+h];
        float wq = fminf(1.f, fmaxf(-1.f, rintf(w/mean)));   // round-half-even like jnp.round
        float wg = ge*wq;
        ushort hh = f2bf(wg);
        Wg_hi[(size_t)(br*64+h)*1024 + t] = hh;
        Wg_lo[(size_t)(br*64+h)*1024 + t] = f2bf(wg - bf2f(hh));
    }
    // col sums: colsumg[h]=sum_e g*wq ; cvec[h]=sum_e b*wq
    const int h2 = t & 63, chunk = t >> 6;
    float cg = 0.f, cb = 0.f;
    for (int i=0;i<64;i++){
        int e = chunk*64 + i;
        float w  = W[e*64+h2];
        float wq = fminf(1.f, fmaxf(-1.f, rintf(w/mean)));
        cg += g[e]*wq;
        cb += bb[e]*wq;
    }
    __shared__ float credg[16][64];
    __shared__ float credb[16][64];
    credg[chunk][h2] = cg;
    credb[chunk][h2] = cb;
    __syncthreads();
    if (t < 64){
        float sg = 0.f, sb = 0.f;
        #pragma unroll
        for (int i=0;i<16;i++){ sg += credg[i][t]; sb += credb[i][t]; }
        colsumg[br*64 + t] = sg;
        cvec[br*64 + t]    = sb;
    }
}

// ---------------- MFMA LN-GEMM ----------------
// out[t,h] = rs_t*(sum_e x[t,e]*Wg[e,h] - mu_t*colsumg[h]) + cvec[h]
// BM=64 (4 waves x 16 rows), BK=64, N=192. x split hi/lo bf16 inline; 3-term MFMA.
// LDS rows are 128B with XOR swizzle ^((row&7)<<4) (same as attn, validated).
__global__ __launch_bounds__(256) void lngemm_k(
    const float* __restrict__ x, const ushort* __restrict__ Wg_hi,
    const ushort* __restrict__ Wg_lo, const float* __restrict__ colsumg,
    const float* __restrict__ cvec, float* __restrict__ qf,
    ushort* __restrict__ khi, ushort* __restrict__ klo,
    ushort* __restrict__ vthi, ushort* __restrict__ vtlo)
{
    __shared__ char smem[65536];   // Ah 8K | Al 8K | Bh 24K | Bl 24K
    __shared__ float mu_s[64], rs_s[64];
    char* Ah = smem;
    char* Al = smem + 8192;
    char* Bh = smem + 16384;
    char* Bl = smem + 40960;

    const int t  = threadIdx.x;
    const int r0 = blockIdx.x * 64;
    const int lane = t & 63, w = t >> 6, lr = lane & 15, lq = lane >> 4;
    const int arow = t >> 2, apart = t & 3;

    // ---- prefetch kt=0 ----
    float4 ax[4];
    {
        const float* xp = x + (size_t)(r0+arow)*1024 + apart*16;
        ax[0]=*(const float4*)(xp);   ax[1]=*(const float4*)(xp+4);
        ax[2]=*(const float4*)(xp+8); ax[3]=*(const float4*)(xp+12);
    }
    uint4 bhv[3][2], blv[3][2];
    #pragma unroll
    for (int cc=0;cc<3;cc++){
        int id = cc*256 + t; int brow = id>>2; int bpart = id&3;
        const ushort* ph = Wg_hi + (size_t)brow*1024 + bpart*16;
        const ushort* pl = Wg_lo + (size_t)brow*1024 + bpart*16;
        bhv[cc][0]=*(const uint4*)(ph); bhv[cc][1]=*(const uint4*)(ph+8);
        blv[cc][0]=*(const uint4*)(pl); blv[cc][1]=*(const uint4*)(pl+8);
    }

    // ---- LN stats (4 threads per row) ----
    {
        const float* xr = x + (size_t)(r0 + arow)*1024 + apart*4;
        float s1=0.f, s2=0.f;
        #pragma unroll 8
        for (int j=0;j<64;j++){
            float4 v = *(const float4*)(xr + j*16);
            s1 += v.x+v.y+v.z+v.w;
            s2 += v.x*v.x+v.y*v.y+v.z*v.z+v.w*v.w;
        }
        s1 += __shfl_xor(s1,1); s1 += __shfl_xor(s1,2);
        s2 += __shfl_xor(s2,1); s2 += __shfl_xor(s2,2);
        if (apart==0){
            float mu  = s1*(1.f/1024.f);
            float var = s2*(1.f/1024.f) - mu*mu;
            mu_s[arow]=mu; rs_s[arow]=rsqrtf(var+LN_EPS);
        }
    }

    f32x4 acc[12];
    #pragma unroll
    for (int n=0;n<12;n++) acc[n] = (f32x4){0.f,0.f,0.f,0.f};

    const int aswz = (arow&7)<<4;

    for (int kt=0; kt<16; kt++){
        // ---- staged regs -> LDS (split x into hi/lo bf16) ----
        {
            float xs[16] = {ax[0].x,ax[0].y,ax[0].z,ax[0].w,
                            ax[1].x,ax[1].y,ax[1].z,ax[1].w,
                            ax[2].x,ax[2].y,ax[2].z,ax[2].w,
                            ax[3].x,ax[3].y,ax[3].z,ax[3].w};
            uint hu[8], lu[8];
            #pragma unroll
            for (int j=0;j<8;j++){
                ushort h0 = f2bf(xs[2*j]),   h1 = f2bf(xs[2*j+1]);
                ushort l0 = f2bf(xs[2*j]  - bf2f(h0));
                ushort l1 = f2bf(xs[2*j+1]- bf2f(h1));
                hu[j] = (uint)h0 | ((uint)h1<<16);
                lu[j] = (uint)l0 | ((uint)l1<<16);
            }
            *(uint4*)(Ah + arow*128 + ((apart*32)    ^ aswz)) = (uint4){hu[0],hu[1],hu[2],hu[3]};
            *(uint4*)(Ah + arow*128 + ((apart*32+16) ^ aswz)) = (uint4){hu[4],hu[5],hu[6],hu[7]};
            *(uint4*)(Al + arow*128 + ((apart*32)    ^ aswz)) = (uint4){lu[0],lu[1],lu[2],lu[3]};
            *(uint4*)(Al + arow*128 + ((apart*32+16) ^ aswz)) = (uint4){lu[4],lu[5],lu[6],lu[7]};
            #pragma unroll
            for (int cc=0;cc<3;cc++){
                int id = cc*256 + t; int brow = id>>2; int bpart = id&3;
                int bswz = (brow&7)<<4;
                *(uint4*)(Bh + brow*128 + ((bpart*32)    ^ bswz)) = bhv[cc][0];
                *(uint4*)(Bh + brow*128 + ((bpart*32+16) ^ bswz)) = bhv[cc][1];
                *(uint4*)(Bl + brow*128 + ((bpart*32)    ^ bswz)) = blv[cc][0];
                *(uint4*)(Bl + brow*128 + ((bpart*32+16) ^ bswz)) = blv[cc][1];
            }
        }
        __syncthreads();
        if (kt < 15){
            const float* xp = x + (size_t)(r0+arow)*1024 + (kt+1)*64 + apart*16;
            ax[0]=*(const float4*)(xp);   ax[1]=*(const float4*)(xp+4);
            ax[2]=*(const float4*)(xp+8); ax[3]=*(const float4*)(xp+12);
            #pragma unroll
            for (int cc=0;cc<3;cc++){
                int id = cc*256 + t; int brow = id>>2; int bpart = id&3;
                const ushort* ph = Wg_hi + (size_t)brow*1024 + (kt+1)*64 + bpart*16;
                const ushort* pl = Wg_lo + (size_t)brow*1024 + (kt+1)*64 + bpart*16;
                bhv[cc][0]=*(const uint4*)(ph); bhv[cc][1]=*(const uint4*)(ph+8);
                blv[cc][0]=*(const uint4*)(pl); blv[cc][1]=*(const uint4*)(pl+8);
            }
        }
        // ---- MFMA: 2 k-chunks x 12 n-frags x 3 terms ----
        #pragma unroll
        for (int kc=0;kc<2;kc++){
            const int abc = kc*64 + lq*16;
            const int ar  = w*16 + lr;
            const int aoff = ar*128 + (abc ^ ((ar&7)<<4));
            bf16x8 ah = *(const bf16x8*)(Ah + aoff);
            bf16x8 al = *(const bf16x8*)(Al + aoff);
            #pragma unroll
            for (int n=0;n<12;n++){
                const int br2 = n*16 + lr;
                const int boff = br2*128 + (abc ^ ((br2&7)<<4));
                bf16x8 bh = *(const bf16x8*)(Bh + boff);
                bf16x8 bl = *(const bf16x8*)(Bl + boff);
                acc[n] = __builtin_amdgcn_mfma_f32_16x16x32_bf16(ah, bh, acc[n], 0,0,0);
                acc[n] = __builtin_amdgcn_mfma_f32_16x16x32_bf16(al, bh, acc[n], 0,0,0);
                acc[n] = __builtin_amdgcn_mfma_f32_16x16x32_bf16(ah, bl, acc[n], 0,0,0);
            }
        }
        __syncthreads();
    }

    // ---- epilogue: LN affine + bias, write q/k/v in attn formats ----
    #pragma unroll
    for (int n=0;n<12;n++){
        const int col = n*16 + lr;
        const float csg = colsumg[col];
        const float cv  = cvec[col];
        #pragma unroll
        for (int i=0;i<4;i++){
            const int lrow = w*16 + lq*4 + i;
            const int grow = r0 + lrow;
            float val = rs_s[lrow]*(acc[n][i] - mu_s[lrow]*csg) + cv;
            if (col < 64){
                qf[(size_t)grow*64 + col] = val;
            } else if (col < 128){
                ushort hh = f2bf(val);
                khi[(size_t)grow*64 + (col-64)] = hh;
                klo[(size_t)grow*64 + (col-64)] = f2h(val - bf2f(hh));
            } else {
                const int b2 = grow >> 12, tt = grow & 4095, hcol = col - 128;
                ushort hh = f2bf(val);
                vthi[((size_t)b2*64 + hcol)*4096 + tt] = hh;
                vtlo[((size_t)b2*64 + hcol)*4096 + tt] = f2bf(val - bf2f(hh));
            }
        }
    }
}

// ---------------- split-K flash attention, MFMA hi/lo ----------------
__global__ __launch_bounds__(256, 2) void attn_mfma_k(
    const float* __restrict__ qf, const ushort* __restrict__ khi,
    const ushort* __restrict__ klo, const ushort* __restrict__ vthi,
    const ushort* __restrict__ vtlo, float* __restrict__ Opart,
    float* __restrict__ ml, int tps)
{
    __shared__ char smem[32768];

    const int t    = threadIdx.x;
    const int lane = t & 63;
    const int w    = t >> 6;
    const int lr   = lane & 15;
    const int lq   = lane >> 4;

    const int bid = blockIdx.x, nwg = gridDim.x;
    const int virt = (bid & 7) * (nwg >> 3) + (bid >> 3);   // XCD-contiguous (nwg%8==0)
    const int ks = virt >> 8;
    const int b  = (virt >> 6) & 3;
    const int qt = virt & 63;

    const int gq = b*4096 + qt*64 + w*16 + lr;
    bf16x8 aqh[2]; f16x8 aqh16[2], aql16[2];
    #pragma unroll
    for (int ks2=0; ks2<2; ks2++){
        const float* qp = qf + (size_t)gq*64 + ks2*32 + lq*8;
        float4 qa = *(const float4*)(qp);
        float4 qb = *(const float4*)(qp+4);
        float qv[8] = {qa.x,qa.y,qa.z,qa.w,qb.x,qb.y,qb.z,qb.w};
        #pragma unroll
        for (int j=0;j<8;j++){
            float q = qv[j] * 0.125f;
            ushort hb = f2bf(q);
            float  hf = bf2f(hb);
            aqh[ks2][j]   = (short)hb;
            aqh16[ks2][j] = (_Float16)hf;
            aql16[ks2][j] = (_Float16)(q - hf);
        }
    }

    float m_[4], l_[4];
    f32x4 Oacc[4];
    #pragma unroll
    for (int i=0;i<4;i++){ m_[i] = -3.0e38f; l_[i] = 0.f; }
    #pragma unroll
    for (int n=0;n<4;n++) Oacc[n] = (f32x4){0.f,0.f,0.f,0.f};

    const int srow = t >> 2;
    const int sseg = (t & 3) * 32;
    const int sd0 = srow*128 + (sseg ^ ((srow&7)<<4));
    const int sd1 = srow*128 + ((sseg+16) ^ ((srow&7)<<4));

    for (int kt = ks*tps; kt < ks*tps + tps; kt++){
        __syncthreads();
        {
            const int grow = b*4096 + kt*64 + srow;
            const char* skh = (const char*)(khi + (size_t)grow*64) + sseg;
            const char* skl = (const char*)(klo + (size_t)grow*64) + sseg;
            const char* svh = (const char*)(vthi + ((size_t)b*64 + srow)*4096 + kt*64) + sseg;
            const char* svl = (const char*)(vtlo + ((size_t)b*64 + srow)*4096 + kt*64) + sseg;
            *(uint4*)(smem         + sd0) = *(const uint4*)(skh);
            *(uint4*)(smem         + sd1) = *(const uint4*)(skh+16);
            *(uint4*)(smem +  8192 + sd0) = *(const uint4*)(skl);
            *(uint4*)(smem +  8192 + sd1) = *(const uint4*)(skl+16);
            *(uint4*)(smem + 16384 + sd0) = *(const uint4*)(svh);
            *(uint4*)(smem + 16384 + sd1) = *(const uint4*)(svh+16);
            *(uint4*)(smem + 24576 + sd0) = *(const uint4*)(svl);
            *(uint4*)(smem + 24576 + sd1) = *(const uint4*)(svl+16);
        }
        __syncthreads();

        f32x4 sacc[4];
        #pragma unroll
        for (int n=0;n<4;n++) sacc[n] = (f32x4){0.f,0.f,0.f,0.f};
        #pragma unroll
        for (int ks2=0; ks2<2; ks2++){
            #pragma unroll
            for (int n=0;n<4;n++){
                const int row = n*16 + lr;
                const int bc  = (ks2*32 + lq*8)*2;
                const int off = row*128 + (bc ^ ((row&7)<<4));
                bf16x8 bkh = *(const bf16x8*)(smem + off);
                f16x8  bkl = *(const f16x8*)(smem + 8192 + off);
                f16x8  bkh16;
                #pragma unroll
                for (int j=0;j<8;j++) bkh16[j] = (_Float16)bf2f((ushort)bkh[j]);
                sacc[n] = __builtin_amdgcn_mfma_f32_16x16x32_bf16(aqh[ks2],  bkh,   sacc[n], 0,0,0);
                sacc[n] = __builtin_amdgcn_mfma_f32_16x16x32_f16 (aqh16[ks2], bkl,  sacc[n], 0,0,0);
                sacc[n] = __builtin_amdgcn_mfma_f32_16x16x32_f16 (aql16[ks2], bkh16,sacc[n], 0,0,0);
                sacc[n] = __builtin_amdgcn_mfma_f32_16x16x32_f16 (aql16[ks2], bkl,  sacc[n], 0,0,0);
            }
        }

        float pvals[4][4];
        float al[4];
        #pragma unroll
        for (int i=0;i<4;i++){
            float tm = fmaxf(fmaxf(sacc[0][i],sacc[1][i]), fmaxf(sacc[2][i],sacc[3][i]));
            tm = fmaxf(tm, __shfl_xor(tm,1));
            tm = fmaxf(tm, __shfl_xor(tm,2));
            tm = fmaxf(tm, __shfl_xor(tm,4));
            tm = fmaxf(tm, __shfl_xor(tm,8));
            float mn = fmaxf(m_[i], tm);
            float a  = __expf(m_[i] - mn);
            float rs = 0.f;
            #pragma unroll
            for (int n=0;n<4;n++){
                float p = __expf(sacc[n][i] - mn);
                pvals[n][i] = p;
                rs += p;
            }
            rs += __shfl_xor(rs,1);
            rs += __shfl_xor(rs,2);
            rs += __shfl_xor(rs,4);
            rs += __shfl_xor(rs,8);
            l_[i] = l_[i]*a + rs;
            m_[i] = mn;
            al[i] = a;
        }
        #pragma unroll
        for (int n=0;n<4;n++){
            #pragma unroll
            for (int i=0;i<4;i++) Oacc[n][i] *= al[i];
        }

        __syncthreads();
        char* Pw = smem + w*4096;
        #pragma unroll
        for (int n=0;n<4;n++){
            #pragma unroll
            for (int i=0;i<4;i++){
                const int row = lq*4 + i;
                const int bc  = (n*16 + lr)*4;
                float  p  = pvals[n][i];
                ushort ph = f2bf(p);
                ushort pl = f2bf(p - bf2f(ph));
                *(uint*)(Pw + row*256 + (bc ^ ((row&7)<<4))) = (uint)ph | ((uint)pl << 16);
            }
        }
        asm volatile("s_waitcnt lgkmcnt(0)" ::: "memory");

        #pragma unroll
        for (int ks2=0; ks2<2; ks2++){
            const int pbc = ks2*128 + lq*32;
            uint4 pv0 = *(const uint4*)(Pw + lr*256 + ( pbc      ^ ((lr&7)<<4)));
            uint4 pv1 = *(const uint4*)(Pw + lr*256 + ((pbc+16)  ^ ((lr&7)<<4)));
            uint pu[8] = {pv0.x,pv0.y,pv0.z,pv0.w,pv1.x,pv1.y,pv1.z,pv1.w};
            bf16x8 ph, pl;
            #pragma unroll
            for (int j=0;j<8;j++){
                ph[j] = (short)(pu[j] & 0xffffu);
                pl[j] = (short)(pu[j] >> 16);
            }
            #pragma unroll
            for (int n=0;n<4;n++){
                const int row = n*16 + lr;
                const int bc  = (ks2*32 + lq*8)*2;
                const int off = row*128 + (bc ^ ((row&7)<<4));
                bf16x8 bvh = *(const bf16x8*)(smem + 16384 + off);
                bf16x8 bvl = *(const bf16x8*)(smem + 24576 + off);
                Oacc[n] = __builtin_amdgcn_mfma_f32_16x16x32_bf16(ph, bvh, Oacc[n], 0,0,0);
                Oacc[n] = __builtin_amdgcn_mfma_f32_16x16x32_bf16(ph, bvl, Oacc[n], 0,0,0);
                Oacc[n] = __builtin_amdgcn_mfma_f32_16x16x32_bf16(pl, bvh, Oacc[n], 0,0,0);
            }
        }
    }

    #pragma unroll
    for (int n=0;n<4;n++){
        #pragma unroll
        for (int i=0;i<4;i++){
            const int row = b*4096 + qt*64 + w*16 + lq*4 + i;
            Opart[((size_t)ks*16384 + row)*64 + n*16 + lr] = Oacc[n][i];
        }
    }
    if (lr == 0){
        #pragma unroll
        for (int i=0;i<4;i++){
            const int row = b*4096 + qt*64 + w*16 + lq*4 + i;
            ml[((size_t)ks*16384 + row)*2 + 0] = m_[i];
            ml[((size_t)ks*16384 + row)*2 + 1] = l_[i];
        }
    }
}

// ---------------- combine split-K partials ----------------
__global__ __launch_bounds__(256) void combine_k(
    const float* __restrict__ Opart, const float* __restrict__ ml,
    float* __restrict__ out, int nsplit)
{
    const int t = threadIdx.x;
    const int tx = t & 15, ty = t >> 4;
    const int r = blockIdx.x * 16 + ty;
    float mstar = -3.0e38f;
    for (int s=0;s<nsplit;s++)
        mstar = fmaxf(mstar, ml[((size_t)s*16384 + r)*2]);
    float lstar = 0.f;
    float4 o = make_float4(0.f,0.f,0.f,0.f);
    for (int s=0;s<nsplit;s++){
        float ms = ml[((size_t)s*16384 + r)*2];
        float ls = ml[((size_t)s*16384 + r)*2 + 1];
        float wgt = __expf(ms - mstar);
        lstar += wgt * ls;
        float4 p = *(const float4*)(Opart + ((size_t)s*16384 + r)*64 + tx*4);
        o.x += wgt*p.x; o.y += wgt*p.y; o.z += wgt*p.z; o.w += wgt*p.w;
    }
    float inv = 1.0f / lstar;
    o.x*=inv; o.y*=inv; o.z*=inv; o.w*=inv;
    *(float4*)(out + (size_t)r*64 + tx*4) = o;
}

extern "C" void kernel_launch(void* const* d_in, const int* in_sizes, int n_in,
                              void* d_out, int out_size, void* d_ws, size_t ws_size,
                              hipStream_t stream) {
    const float* x  = (const float*)d_in[0];
    const float* Wk = (const float*)d_in[1];
    const float* Wq = (const float*)d_in[2];
    const float* Wv = (const float*)d_in[3];
    const float* gk = (const float*)d_in[4];
    const float* bk = (const float*)d_in[5];
    const float* gq = (const float*)d_in[6];
    const float* bq = (const float*)d_in[7];
    const float* gv = (const float*)d_in[8];
    const float* bv = (const float*)d_in[9];
    float* out = (float*)d_out;
    char* ws = (char*)d_ws;
    ushort* Wg_hi   = (ushort*)(ws);
    ushort* Wg_lo   = (ushort*)(ws + 393216);
    float*  colsumg = (float*)(ws + 786432);
    float*  cvec    = (float*)(ws + 787200);
    float*  qf   = (float*)(ws + 1048576);
    ushort* khi  = (ushort*)(ws + 5242880);
    ushort* klo  = (ushort*)(ws + 7340032);
    ushort* vthi = (ushort*)(ws + 9437184);
    ushort* vtlo = (ushort*)(ws + 11534336);

    const size_t base = 13631488;
    int ns;
    if      (ws_size >= base + 4ull*4325376) ns = 4;
    else if (ws_size >= base + 2ull*4325376) ns = 2;
    else                                     ns = 1;
    float* Opart = (float*)(ws + base);
    float* mlp   = (float*)(ws + base + (size_t)ns*4194304);

    quant_k<<<dim3(3), dim3(1024), 0, stream>>>(Wq, Wk, Wv, gq, bq, gk, bk, gv, bv,
                                                Wg_hi, Wg_lo, colsumg, cvec);
    lngemm_k<<<dim3(256), dim3(256), 0, stream>>>(x, Wg_hi, Wg_lo, colsumg, cvec,
                                                  qf, khi, klo, vthi, vtlo);
    attn_mfma_k<<<dim3(256*ns), dim3(256), 0, stream>>>(qf, khi, klo, vthi, vtlo, Opart, mlp, 64/ns);
    combine_k<<<dim3(1024), dim3(256), 0, stream>>>(Opart, mlp, out, ns);
}

// Round 8
// 293.878 us; speedup vs baseline: 2.6485x; 1.1092x over previous
//
#include <hip/hip_runtime.h>
#include <math.h>

#define LN_EPS 1e-5f

typedef __attribute__((ext_vector_type(8))) _Float16 f16x8;
typedef __attribute__((ext_vector_type(4))) float    f32x4;

__device__ inline ushort f2h(float f){            // f32->f16 bits (RNE)
    union { _Float16 h; ushort u; } v; v.h = (_Float16)f;
    return v.u;
}
__device__ inline float h2f(ushort u){
    union { ushort u; _Float16 h; } v; v.u = u;
    return (float)v.h;
}

// ws layout (bytes):
//   Wh16 [192][1024] f16 @ 0        (transposed gamma*ternary, f16 hi)
//   Wl16 [192][1024] f16 @ 393216   (f16 residual; all-zero when gamma*wq is f16-exact)
//   colsumg [192] f32 @ 786432      (sum_e gamma*wq)
//   cvec    [192] f32 @ 787200      (sum_e beta*wq)
//   flags   [3] int   @ 787968      (Wl16 nonzero flag per matrix)
//   qf   [16384][64] f32 @ 1048576
//   kh16 [16384][64] f16 @ 5242880
//   kl16 [16384][64] f16 @ 7340032
//   vth  [4][64][4096] f16 @ 9437184    (per-batch V^T, hi)
//   vtl  [4][64][4096] f16 @ 11534336   (lo)
//   Opart [ns][16384][64] f32 @ 13631488
//   ml    [ns][16384][2]  f32 @ 13631488 + ns*4194304

// ---------------- quantize weights: Wg=gamma*tern (f16 hi/lo, transposed) ----------------
__global__ __launch_bounds__(1024) void quant_k(
    const float* __restrict__ Wq, const float* __restrict__ Wk, const float* __restrict__ Wv,
    const float* __restrict__ gq, const float* __restrict__ bq,
    const float* __restrict__ gk, const float* __restrict__ bk,
    const float* __restrict__ gv, const float* __restrict__ bv,
    ushort* __restrict__ Wh16, ushort* __restrict__ Wl16,
    float* __restrict__ colsumg, float* __restrict__ cvec, int* __restrict__ flags)
{
    const int br = blockIdx.x;                 // 0=q, 1=k, 2=v
    const float* W = (br==0) ? Wq : (br==1 ? Wk : Wv);
    const float* g = (br==0) ? gq : (br==1 ? gk : gv);
    const float* bb= (br==0) ? bq : (br==1 ? bk : bv);
    const int t = threadIdx.x;
    __shared__ float red[1024];
    __shared__ int nzs;
    float s = 0.f;
    #pragma unroll 4
    for (int i=0;i<64;i++) s += fabsf(W[t + 1024*i]);
    red[t] = s;
    if (t==0) nzs = 0;
    __syncthreads();
    for (int o=512;o>0;o>>=1){ if (t<o) red[t]+=red[t+o]; __syncthreads(); }
    const float mean = red[0] * (1.0f/65536.0f);   // exact /2^16

    const float ge = g[t];
    int nz = 0;
    for (int h=0; h<64; h++) {
        float w  = W[t*64+h];
        float wq = fminf(1.f, fmaxf(-1.f, rintf(w/mean)));   // round-half-even like jnp.round
        float wg = ge*wq;
        ushort hh = f2h(wg);
        ushort ll = f2h(wg - h2f(hh));
        Wh16[(size_t)(br*64+h)*1024 + t] = hh;
        Wl16[(size_t)(br*64+h)*1024 + t] = ll;
        nz |= (int)(ll & 0x7fffu);
    }
    if (nz) atomicOr(&nzs, 1);
    // col sums: colsumg[h]=sum_e g*wq ; cvec[h]=sum_e b*wq
    const int h2 = t & 63, chunk = t >> 6;
    float cg = 0.f, cb = 0.f;
    for (int i=0;i<64;i++){
        int e = chunk*64 + i;
        float w  = W[e*64+h2];
        float wq = fminf(1.f, fmaxf(-1.f, rintf(w/mean)));
        cg += g[e]*wq;
        cb += bb[e]*wq;
    }
    __shared__ float credg[16][64];
    __shared__ float credb[16][64];
    credg[chunk][h2] = cg;
    credb[chunk][h2] = cb;
    __syncthreads();
    if (t < 64){
        float sg = 0.f, sb = 0.f;
        #pragma unroll
        for (int i=0;i<16;i++){ sg += credg[i][t]; sb += credb[i][t]; }
        colsumg[br*64 + t] = sg;
        cvec[br*64 + t]    = sb;
    }
    if (t == 0) flags[br] = nzs;
}

// ---------------- MFMA LN-GEMM (f16 split) ----------------
// out[t,h] = rs_t*(sum_e x[t,e]*Wg[e,h] - mu_t*colsumg[h]) + cvec[h]
// x split into f16 hi/lo inline; terms xh*Wh + xl*Wh (+ xh*Wl if flag).
__global__ __launch_bounds__(256) void lngemm_k(
    const float* __restrict__ x, const ushort* __restrict__ Wh16,
    const ushort* __restrict__ Wl16, const float* __restrict__ colsumg,
    const float* __restrict__ cvec, const int* __restrict__ flags,
    float* __restrict__ qf,
    ushort* __restrict__ kh16, ushort* __restrict__ kl16,
    ushort* __restrict__ vth, ushort* __restrict__ vtl)
{
    __shared__ char smem[65536];   // Ah 8K | Al 8K | Bh 24K | Bl 24K
    __shared__ float mu_s[64], rs_s[64];
    char* Ah = smem;
    char* Al = smem + 8192;
    char* Bh = smem + 16384;
    char* Bl = smem + 40960;

    const int t  = threadIdx.x;
    const int r0 = blockIdx.x * 64;
    const int lane = t & 63, w = t >> 6, lr = lane & 15, lq = lane >> 4;
    const int arow = t >> 2, apart = t & 3;
    const int flag = flags[0] | flags[1] | flags[2];

    // ---- prefetch kt=0 ----
    float4 ax[4];
    {
        const float* xp = x + (size_t)(r0+arow)*1024 + apart*16;
        ax[0]=*(const float4*)(xp);   ax[1]=*(const float4*)(xp+4);
        ax[2]=*(const float4*)(xp+8); ax[3]=*(const float4*)(xp+12);
    }
    uint4 bhv[3][2], blv[3][2];
    #pragma unroll
    for (int cc=0;cc<3;cc++){
        int id = cc*256 + t; int brow = id>>2; int bpart = id&3;
        const ushort* ph = Wh16 + (size_t)brow*1024 + bpart*16;
        bhv[cc][0]=*(const uint4*)(ph); bhv[cc][1]=*(const uint4*)(ph+8);
        if (flag){
            const ushort* pl = Wl16 + (size_t)brow*1024 + bpart*16;
            blv[cc][0]=*(const uint4*)(pl); blv[cc][1]=*(const uint4*)(pl+8);
        }
    }

    // ---- LN stats (4 threads per row) ----
    {
        const float* xr = x + (size_t)(r0 + arow)*1024 + apart*4;
        float s1=0.f, s2=0.f;
        #pragma unroll 8
        for (int j=0;j<64;j++){
            float4 v = *(const float4*)(xr + j*16);
            s1 += v.x+v.y+v.z+v.w;
            s2 += v.x*v.x+v.y*v.y+v.z*v.z+v.w*v.w;
        }
        s1 += __shfl_xor(s1,1); s1 += __shfl_xor(s1,2);
        s2 += __shfl_xor(s2,1); s2 += __shfl_xor(s2,2);
        if (apart==0){
            float mu  = s1*(1.f/1024.f);
            float var = s2*(1.f/1024.f) - mu*mu;
            mu_s[arow]=mu; rs_s[arow]=rsqrtf(var+LN_EPS);
        }
    }

    f32x4 acc[12];
    #pragma unroll
    for (int n=0;n<12;n++) acc[n] = (f32x4){0.f,0.f,0.f,0.f};

    const int aswz = (arow&7)<<4;

    for (int kt=0; kt<16; kt++){
        // ---- staged regs -> LDS (split x into f16 hi/lo) ----
        {
            float xs[16] = {ax[0].x,ax[0].y,ax[0].z,ax[0].w,
                            ax[1].x,ax[1].y,ax[1].z,ax[1].w,
                            ax[2].x,ax[2].y,ax[2].z,ax[2].w,
                            ax[3].x,ax[3].y,ax[3].z,ax[3].w};
            uint hu[8], lu[8];
            #pragma unroll
            for (int j=0;j<8;j++){
                ushort h0 = f2h(xs[2*j]),    h1 = f2h(xs[2*j+1]);
                ushort l0 = f2h(xs[2*j]   - h2f(h0));
                ushort l1 = f2h(xs[2*j+1] - h2f(h1));
                hu[j] = (uint)h0 | ((uint)h1<<16);
                lu[j] = (uint)l0 | ((uint)l1<<16);
            }
            *(uint4*)(Ah + arow*128 + ((apart*32)    ^ aswz)) = (uint4){hu[0],hu[1],hu[2],hu[3]};
            *(uint4*)(Ah + arow*128 + ((apart*32+16) ^ aswz)) = (uint4){hu[4],hu[5],hu[6],hu[7]};
            *(uint4*)(Al + arow*128 + ((apart*32)    ^ aswz)) = (uint4){lu[0],lu[1],lu[2],lu[3]};
            *(uint4*)(Al + arow*128 + ((apart*32+16) ^ aswz)) = (uint4){lu[4],lu[5],lu[6],lu[7]};
            #pragma unroll
            for (int cc=0;cc<3;cc++){
                int id = cc*256 + t; int brow = id>>2; int bpart = id&3;
                int bswz = (brow&7)<<4;
                *(uint4*)(Bh + brow*128 + ((bpart*32)    ^ bswz)) = bhv[cc][0];
                *(uint4*)(Bh + brow*128 + ((bpart*32+16) ^ bswz)) = bhv[cc][1];
                if (flag){
                    *(uint4*)(Bl + brow*128 + ((bpart*32)    ^ bswz)) = blv[cc][0];
                    *(uint4*)(Bl + brow*128 + ((bpart*32+16) ^ bswz)) = blv[cc][1];
                }
            }
        }
        __syncthreads();
        if (kt < 15){
            const float* xp = x + (size_t)(r0+arow)*1024 + (kt+1)*64 + apart*16;
            ax[0]=*(const float4*)(xp);   ax[1]=*(const float4*)(xp+4);
            ax[2]=*(const float4*)(xp+8); ax[3]=*(const float4*)(xp+12);
            #pragma unroll
            for (int cc=0;cc<3;cc++){
                int id = cc*256 + t; int brow = id>>2; int bpart = id&3;
                const ushort* ph = Wh16 + (size_t)brow*1024 + (kt+1)*64 + bpart*16;
                bhv[cc][0]=*(const uint4*)(ph); bhv[cc][1]=*(const uint4*)(ph+8);
                if (flag){
                    const ushort* pl = Wl16 + (size_t)brow*1024 + (kt+1)*64 + bpart*16;
                    blv[cc][0]=*(const uint4*)(pl); blv[cc][1]=*(const uint4*)(pl+8);
                }
            }
        }
        // ---- MFMA: 2 k-chunks x 12 n-frags x (2 or 3) terms ----
        #pragma unroll
        for (int kc=0;kc<2;kc++){
            const int abc = kc*64 + lq*16;
            const int ar  = w*16 + lr;
            const int aoff = ar*128 + (abc ^ ((ar&7)<<4));
            f16x8 ah = *(const f16x8*)(Ah + aoff);
            f16x8 al = *(const f16x8*)(Al + aoff);
            #pragma unroll
            for (int n=0;n<12;n++){
                const int br2 = n*16 + lr;
                const int boff = br2*128 + (abc ^ ((br2&7)<<4));
                f16x8 bh = *(const f16x8*)(Bh + boff);
                acc[n] = __builtin_amdgcn_mfma_f32_16x16x32_f16(ah, bh, acc[n], 0,0,0);
                acc[n] = __builtin_amdgcn_mfma_f32_16x16x32_f16(al, bh, acc[n], 0,0,0);
                if (flag){
                    f16x8 bl = *(const f16x8*)(Bl + boff);
                    acc[n] = __builtin_amdgcn_mfma_f32_16x16x32_f16(ah, bl, acc[n], 0,0,0);
                }
            }
        }
        __syncthreads();
    }

    // ---- epilogue: LN affine + bias, write q/k/v in attn formats ----
    #pragma unroll
    for (int n=0;n<12;n++){
        const int col = n*16 + lr;
        const float csg = colsumg[col];
        const float cv  = cvec[col];
        #pragma unroll
        for (int i=0;i<4;i++){
            const int lrow = w*16 + lq*4 + i;
            const int grow = r0 + lrow;
            float val = rs_s[lrow]*(acc[n][i] - mu_s[lrow]*csg) + cv;
            if (col < 64){
                qf[(size_t)grow*64 + col] = val;
            } else if (col < 128){
                ushort hh = f2h(val);
                kh16[(size_t)grow*64 + (col-64)] = hh;
                kl16[(size_t)grow*64 + (col-64)] = f2h(val - h2f(hh));
            } else {
                const int b2 = grow >> 12, tt = grow & 4095, hcol = col - 128;
                ushort hh = f2h(val);
                vth[((size_t)b2*64 + hcol)*4096 + tt] = hh;
                vtl[((size_t)b2*64 + hcol)*4096 + tt] = f2h(val - h2f(hh));
            }
        }
    }
}

// ---------------- split-K flash attention, f16-split MFMA ----------------
// grid = 256*ns; virt = ks*256 + b*64 + qt. 4 waves, each owns 16 q-rows.
// LDS 32 KB: Kh16(8K) | Kl16(8K) | Vh16(8K) | Vl16(8K);
// P (two f16 planes, 2K+2K per wave) aliases K region after S-phase.
// All LDS rows 128 B with 16B-granule XOR swizzle ^((row&7)<<4).
__global__ __launch_bounds__(256, 2) void attn_mfma_k(
    const float* __restrict__ qf, const ushort* __restrict__ kh16,
    const ushort* __restrict__ kl16, const ushort* __restrict__ vth,
    const ushort* __restrict__ vtl, float* __restrict__ Opart,
    float* __restrict__ ml, int tps)
{
    __shared__ char smem[32768];

    const int t    = threadIdx.x;
    const int lane = t & 63;
    const int w    = t >> 6;
    const int lr   = lane & 15;
    const int lq   = lane >> 4;

    const int bid = blockIdx.x, nwg = gridDim.x;
    const int virt = (bid & 7) * (nwg >> 3) + (bid >> 3);   // XCD-contiguous (nwg%8==0)
    const int ks = virt >> 8;
    const int b  = (virt >> 6) & 3;
    const int qt = virt & 63;

    // ---- Q fragments (scale 1/8 folded; f16 hi/lo) ----
    const int gq = b*4096 + qt*64 + w*16 + lr;
    f16x8 aqh[2], aql[2];
    #pragma unroll
    for (int ks2=0; ks2<2; ks2++){
        const float* qp = qf + (size_t)gq*64 + ks2*32 + lq*8;
        float4 qa = *(const float4*)(qp);
        float4 qb = *(const float4*)(qp+4);
        float qv[8] = {qa.x,qa.y,qa.z,qa.w,qb.x,qb.y,qb.z,qb.w};
        #pragma unroll
        for (int j=0;j<8;j++){
            float q = qv[j] * 0.125f;
            _Float16 qh = (_Float16)q;
            aqh[ks2][j] = qh;
            aql[ks2][j] = (_Float16)(q - (float)qh);
        }
    }

    float m_[4], l_[4];
    f32x4 Oacc[4];
    #pragma unroll
    for (int i=0;i<4;i++){ m_[i] = -3.0e38f; l_[i] = 0.f; }
    #pragma unroll
    for (int n=0;n<4;n++) Oacc[n] = (f32x4){0.f,0.f,0.f,0.f};

    const int srow = t >> 2;
    const int sseg = (t & 3) * 32;
    const int sd0 = srow*128 + (sseg ^ ((srow&7)<<4));
    const int sd1 = srow*128 + ((sseg+16) ^ ((srow&7)<<4));

    for (int kt = ks*tps; kt < ks*tps + tps; kt++){
        __syncthreads();
        {
            const int grow = b*4096 + kt*64 + srow;
            const char* skh = (const char*)(kh16 + (size_t)grow*64) + sseg;
            const char* skl = (const char*)(kl16 + (size_t)grow*64) + sseg;
            const char* svh = (const char*)(vth + ((size_t)b*64 + srow)*4096 + kt*64) + sseg;
            const char* svl = (const char*)(vtl + ((size_t)b*64 + srow)*4096 + kt*64) + sseg;
            *(uint4*)(smem         + sd0) = *(const uint4*)(skh);
            *(uint4*)(smem         + sd1) = *(const uint4*)(skh+16);
            *(uint4*)(smem +  8192 + sd0) = *(const uint4*)(skl);
            *(uint4*)(smem +  8192 + sd1) = *(const uint4*)(skl+16);
            *(uint4*)(smem + 16384 + sd0) = *(const uint4*)(svh);
            *(uint4*)(smem + 16384 + sd1) = *(const uint4*)(svh+16);
            *(uint4*)(smem + 24576 + sd0) = *(const uint4*)(svl);
            *(uint4*)(smem + 24576 + sd1) = *(const uint4*)(svl+16);
        }
        __syncthreads();

        // ---- S = Q·K^T : 3 f16 split terms ----
        f32x4 sacc[4];
        #pragma unroll
        for (int n=0;n<4;n++) sacc[n] = (f32x4){0.f,0.f,0.f,0.f};
        #pragma unroll
        for (int ks2=0; ks2<2; ks2++){
            #pragma unroll
            for (int n=0;n<4;n++){
                const int row = n*16 + lr;
                const int bc  = (ks2*32 + lq*8)*2;
                const int off = row*128 + (bc ^ ((row&7)<<4));
                f16x8 bkh = *(const f16x8*)(smem + off);
                f16x8 bkl = *(const f16x8*)(smem + 8192 + off);
                sacc[n] = __builtin_amdgcn_mfma_f32_16x16x32_f16(aqh[ks2], bkh, sacc[n], 0,0,0);
                sacc[n] = __builtin_amdgcn_mfma_f32_16x16x32_f16(aql[ks2], bkh, sacc[n], 0,0,0);
                sacc[n] = __builtin_amdgcn_mfma_f32_16x16x32_f16(aqh[ks2], bkl, sacc[n], 0,0,0);
            }
        }

        // ---- online softmax (C-layout: row=(lq*4+i), col=lr+16n) ----
        float pvals[4][4];
        float al[4];
        #pragma unroll
        for (int i=0;i<4;i++){
            float tm = fmaxf(fmaxf(sacc[0][i],sacc[1][i]), fmaxf(sacc[2][i],sacc[3][i]));
            tm = fmaxf(tm, __shfl_xor(tm,1));
            tm = fmaxf(tm, __shfl_xor(tm,2));
            tm = fmaxf(tm, __shfl_xor(tm,4));
            tm = fmaxf(tm, __shfl_xor(tm,8));
            float mn = fmaxf(m_[i], tm);
            float a  = __expf(m_[i] - mn);
            float rs = 0.f;
            #pragma unroll
            for (int n=0;n<4;n++){
                float p = __expf(sacc[n][i] - mn);
                pvals[n][i] = p;
                rs += p;
            }
            rs += __shfl_xor(rs,1);
            rs += __shfl_xor(rs,2);
            rs += __shfl_xor(rs,4);
            rs += __shfl_xor(rs,8);
            l_[i] = l_[i]*a + rs;
            m_[i] = mn;
            al[i] = a;
        }
        #pragma unroll
        for (int n=0;n<4;n++){
            #pragma unroll
            for (int i=0;i<4;i++) Oacc[n][i] *= al[i];
        }

        // ---- P -> LDS as two f16 planes (aliases K region) ----
        __syncthreads();
        char* Ph = smem + w*4096;          // [16 rows][64 f16] = 2 KB
        char* Pl = Ph + 2048;
        #pragma unroll
        for (int n=0;n<4;n++){
            #pragma unroll
            for (int i=0;i<4;i++){
                const int row = lq*4 + i;
                const int bc  = (n*16 + lr)*2;
                const int ad  = row*128 + (bc ^ ((row&7)<<4));
                float  p   = pvals[n][i];
                ushort ph_ = f2h(p);
                *(ushort*)(Ph + ad) = ph_;
                *(ushort*)(Pl + ad) = f2h(p - h2f(ph_));
            }
        }
        asm volatile("s_waitcnt lgkmcnt(0)" ::: "memory");   // own-wave P writes visible

        // ---- O += P·V : 3 f16 split terms ----
        #pragma unroll
        for (int ks2=0; ks2<2; ks2++){
            const int pbyte = ks2*64 + lq*16;
            const int poff  = lr*128 + (pbyte ^ ((lr&7)<<4));
            f16x8 ph = *(const f16x8*)(Ph + poff);
            f16x8 pl = *(const f16x8*)(Pl + poff);
            #pragma unroll
            for (int n=0;n<4;n++){
                const int row = n*16 + lr;
                const int bc  = (ks2*32 + lq*8)*2;
                const int off = row*128 + (bc ^ ((row&7)<<4));
                f16x8 bvh = *(const f16x8*)(smem + 16384 + off);
                f16x8 bvl = *(const f16x8*)(smem + 24576 + off);
                Oacc[n] = __builtin_amdgcn_mfma_f32_16x16x32_f16(ph, bvh, Oacc[n], 0,0,0);
                Oacc[n] = __builtin_amdgcn_mfma_f32_16x16x32_f16(ph, bvl, Oacc[n], 0,0,0);
                Oacc[n] = __builtin_amdgcn_mfma_f32_16x16x32_f16(pl, bvh, Oacc[n], 0,0,0);
            }
        }
    }

    // ---- epilogue: unnormalized partials + (m,l) ----
    #pragma unroll
    for (int n=0;n<4;n++){
        #pragma unroll
        for (int i=0;i<4;i++){
            const int row = b*4096 + qt*64 + w*16 + lq*4 + i;
            Opart[((size_t)ks*16384 + row)*64 + n*16 + lr] = Oacc[n][i];
        }
    }
    if (lr == 0){
        #pragma unroll
        for (int i=0;i<4;i++){
            const int row = b*4096 + qt*64 + w*16 + lq*4 + i;
            ml[((size_t)ks*16384 + row)*2 + 0] = m_[i];
            ml[((size_t)ks*16384 + row)*2 + 1] = l_[i];
        }
    }
}

// ---------------- combine split-K partials ----------------
__global__ __launch_bounds__(256) void combine_k(
    const float* __restrict__ Opart, const float* __restrict__ ml,
    float* __restrict__ out, int nsplit)
{
    const int t = threadIdx.x;
    const int tx = t & 15, ty = t >> 4;
    const int r = blockIdx.x * 16 + ty;
    float mstar = -3.0e38f;
    for (int s=0;s<nsplit;s++)
        mstar = fmaxf(mstar, ml[((size_t)s*16384 + r)*2]);
    float lstar = 0.f;
    float4 o = make_float4(0.f,0.f,0.f,0.f);
    for (int s=0;s<nsplit;s++){
        float ms = ml[((size_t)s*16384 + r)*2];
        float ls = ml[((size_t)s*16384 + r)*2 + 1];
        float wgt = __expf(ms - mstar);
        lstar += wgt * ls;
        float4 p = *(const float4*)(Opart + ((size_t)s*16384 + r)*64 + tx*4);
        o.x += wgt*p.x; o.y += wgt*p.y; o.z += wgt*p.z; o.w += wgt*p.w;
    }
    float inv = 1.0f / lstar;
    o.x*=inv; o.y*=inv; o.z*=inv; o.w*=inv;
    *(float4*)(out + (size_t)r*64 + tx*4) = o;
}

extern "C" void kernel_launch(void* const* d_in, const int* in_sizes, int n_in,
                              void* d_out, int out_size, void* d_ws, size_t ws_size,
                              hipStream_t stream) {
    const float* x  = (const float*)d_in[0];
    const float* Wk = (const float*)d_in[1];
    const float* Wq = (const float*)d_in[2];
    const float* Wv = (const float*)d_in[3];
    const float* gk = (const float*)d_in[4];
    const float* bk = (const float*)d_in[5];
    const float* gq = (const float*)d_in[6];
    const float* bq = (const float*)d_in[7];
    const float* gv = (const float*)d_in[8];
    const float* bv = (const float*)d_in[9];
    float* out = (float*)d_out;
    char* ws = (char*)d_ws;
    ushort* Wh16    = (ushort*)(ws);
    ushort* Wl16    = (ushort*)(ws + 393216);
    float*  colsumg = (float*)(ws + 786432);
    float*  cvec    = (float*)(ws + 787200);
    int*    flags   = (int*)(ws + 787968);
    float*  qf   = (float*)(ws + 1048576);
    ushort* kh16 = (ushort*)(ws + 5242880);
    ushort* kl16 = (ushort*)(ws + 7340032);
    ushort* vth  = (ushort*)(ws + 9437184);
    ushort* vtl  = (ushort*)(ws + 11534336);

    const size_t base = 13631488;
    int ns;
    if      (ws_size >= base + 4ull*4325376) ns = 4;
    else if (ws_size >= base + 2ull*4325376) ns = 2;
    else                                     ns = 1;
    float* Opart = (float*)(ws + base);
    float* mlp   = (float*)(ws + base + (size_t)ns*4194304);

    quant_k<<<dim3(3), dim3(1024), 0, stream>>>(Wq, Wk, Wv, gq, bq, gk, bk, gv, bv,
                                                Wh16, Wl16, colsumg, cvec, flags);
    lngemm_k<<<dim3(256), dim3(256), 0, stream>>>(x, Wh16, Wl16, colsumg, cvec, flags,
                                                  qf, kh16, kl16, vth, vtl);
    attn_mfma_k<<<dim3(256*ns), dim3(256), 0, stream>>>(qf, kh16, kl16, vth, vtl, Opart, mlp, 64/ns);
    combine_k<<<dim3(1024), dim3(256), 0, stream>>>(Opart, mlp, out, ns);
}